// Round 1
// baseline (1738.762 us; speedup 1.0000x reference)
//
#include <hip/hip_runtime.h>
#include <hip/hip_bf16.h>

#define BB 4
#define CC 64
#define OO 64
#define NN 32768
#define TT 4
#define KK 9
#define PADW 4
#define SIGMA 0.05f
#define EPS_BN 1e-5f

#define TN 128   // n-tile for conv kernel

// ws layout (bytes):
//   [0,    2048): conv_stats   T*O*2 floats (sum, sumsq)   -- zeroed each launch
//   [2048, 2560): fusion_stats O*2 floats                  -- zeroed each launch
//   [4096, 6144): conv scale/shift T*O*2 floats
//   [8192, 8192+67108864): Y bf16, layout (T,B,O,N)

// ---------------------------------------------------------------------------
// Kernel 1: gather + weighted conv + per-(t,o) stat accumulation, bf16 store
// ---------------------------------------------------------------------------
__global__ __launch_bounds__(256) void conv_kernel(
    const float* __restrict__ inp,   // (B,C,N)
    const float* __restrict__ mc,    // (B,3,N,T)
    const int*   __restrict__ ind,   // (B,N,T)
    const float* __restrict__ cw,    // (T,O,C,K)
    __hip_bfloat16* __restrict__ Y,  // (T,B,O,N)
    float* __restrict__ cstats)      // (T*O*2)
{
  const int n0  = blockIdx.x * TN;
  const int b   = blockIdx.y;
  const int t   = blockIdx.z;
  const int tid = threadIdx.x;

  __shared__ float xs[CC][TN + 9];   // gathered x tile, cols 0..TN+7 (stride 137: 137%32 coprime-ish -> conflict-free store)
  __shared__ float wgl[TN][KK];      // wgt[n_local][k]
  __shared__ float sred[2][4][OO];

  // phase A: compute window weights wgt[n,k]
  for (int u = tid; u < TN * KK; u += 256) {
    int nl = u / KK;
    int k  = u - nl * KK;
    int n  = n0 + nl;
    int m  = n + k - PADW;           // original coord index of window slot
    float w = 0.f;
    if (m >= 0 && m < NN) {
      const float cx = mc[((size_t)(b*3+0)*NN + n)*TT + t];
      const float cy = mc[((size_t)(b*3+1)*NN + n)*TT + t];
      const float cz = mc[((size_t)(b*3+2)*NN + n)*TT + t];
      float dx = mc[((size_t)(b*3+0)*NN + m)*TT + t] - cx;
      float dy = mc[((size_t)(b*3+1)*NN + m)*TT + t] - cy;
      float dz = mc[((size_t)(b*3+2)*NN + m)*TT + t] - cz;
      float s = dx*dx + dy*dy + dz*dz;
      float r = (s > 0.f) ? sqrtf(s) : 0.f;
      w = fmaxf(1.f - r * (1.f / SIGMA), 0.f);
    }
    // m out of range => x is zero-padded there, contribution 0 regardless -> w=0 fine
    wgl[nl][k] = w;
  }

  // phase B: gathered x tile  xs[c][col], col = m - (n0-4), m in [n0-4, n0+TN+4)
  for (int u = tid; u < CC * (TN + 8); u += 256) {
    int col = u >> 6;     // 0..TN+7 ; all 64 lanes share col -> idx load broadcasts
    int c   = u & 63;
    int m   = n0 + col - PADW;
    float v = 0.f;
    if (m >= 0 && m < NN) {
      int idx = ind[((size_t)b*NN + m)*TT + t];
      v = inp[((size_t)(b*CC + c))*NN + idx];
    }
    xs[c][col] = v;
  }
  __syncthreads();

  // phase C: factorized conv.  out[o,n] = sum_k wgt[n,k] * (sum_c xs[c][n+k]*w[o,c,k])
  const int o = tid & 63;
  const int j = tid >> 6;
  const int nbase = j * 32;          // this thread covers n_local = nbase..nbase+31

  float acc[32];
  #pragma unroll
  for (int i = 0; i < 32; ++i) acc[i] = 0.f;

  const float* wrow = cw + ((size_t)(t*OO + o)*CC)*KK;
  for (int k = 0; k < KK; ++k) {
    float g[32];
    #pragma unroll
    for (int i = 0; i < 32; ++i) g[i] = 0.f;
    for (int c = 0; c < CC; ++c) {
      float wv = wrow[c*KK + k];
      const float* xr = &xs[c][nbase + k];   // wave-uniform address -> LDS broadcast
      #pragma unroll
      for (int i = 0; i < 32; ++i) g[i] += xr[i] * wv;
    }
    #pragma unroll
    for (int i = 0; i < 32; ++i) acc[i] += wgl[nbase + i][k] * g[i];
  }

  // per-thread stats, then reduce across j and atomically accumulate
  float s1 = 0.f, s2 = 0.f;
  #pragma unroll
  for (int i = 0; i < 32; ++i) { s1 += acc[i]; s2 += acc[i]*acc[i]; }
  sred[0][j][o] = s1;
  sred[1][j][o] = s2;
  __syncthreads();   // also guarantees all xs reads are done (stage reuse below)

  if (tid < OO) {
    float a = sred[0][0][tid] + sred[0][1][tid] + sred[0][2][tid] + sred[0][3][tid];
    float q = sred[1][0][tid] + sred[1][1][tid] + sred[1][2][tid] + sred[1][3][tid];
    atomicAdd(&cstats[(t*OO + tid)*2 + 0], a);
    atomicAdd(&cstats[(t*OO + tid)*2 + 1], q);
  }

  // stage output in LDS (reuse xs region, padded stride 129 -> conflict-free), then coalesced bf16 store
  float (*stage)[129] = (float (*)[129])xs;   // 64*129*4 = 33024 <= 35072 bytes
  #pragma unroll
  for (int i = 0; i < 32; ++i) stage[o][nbase + i] = acc[i];
  __syncthreads();

  const size_t ybase = ((size_t)(t*BB + b)) * OO * NN;
  for (int u = tid; u < OO * TN; u += 256) {
    int oo = u >> 7;       // TN = 128
    int nl = u & 127;
    Y[ybase + (size_t)oo*NN + n0 + nl] = __float2bfloat16(stage[oo][nl]);
  }
}

// ---------------------------------------------------------------------------
// Kernel 2: fold conv BN stats into per-(t,o) scale/shift
// ---------------------------------------------------------------------------
__global__ void bnparam_kernel(const float* __restrict__ cstats,
                               const float* __restrict__ gam,   // (T,O) flat
                               const float* __restrict__ bet,   // (T,O) flat
                               float* __restrict__ ss)          // (T*O,2)
{
  int tid = threadIdx.x;   // 256 = T*O
  float s1 = cstats[tid*2 + 0];
  float s2 = cstats[tid*2 + 1];
  const float inv = 1.f / (float)(BB * NN);
  float mean = s1 * inv;
  float var  = s2 * inv - mean * mean;
  float sc = gam[tid] * rsqrtf(var + EPS_BN);
  ss[tid*2 + 0] = sc;
  ss[tid*2 + 1] = bet[tid] - mean * sc;
}

// ---------------------------------------------------------------------------
// Kernel 3: reindex-gather + BN-apply + fusion matvec + fusion-stat accumulate
// ---------------------------------------------------------------------------
__global__ __launch_bounds__(256) void fusion_kernel(
    const __hip_bfloat16* __restrict__ Y,   // (T,B,O,N)
    const int*   __restrict__ rind,         // (B,N,T)
    const float* __restrict__ ss,           // (T*O,2) scale/shift
    const float* __restrict__ fw,           // (O, T*O)
    const float* __restrict__ fb,           // (O)
    float* __restrict__ out,                // (B,O,N) pre-BN values
    float* __restrict__ fstats)             // (O*2)
{
  const int n0  = blockIdx.x * 64;
  const int b   = blockIdx.y;
  const int tid = threadIdx.x;

  __shared__ float z[128][66];     // half of the 256 cat-channels at a time
  __shared__ int   rnl[TT][64];
  __shared__ float sred[2][4][64];

  {
    int t = tid >> 6, n = tid & 63;
    rnl[t][n] = rind[((size_t)b*NN + n0 + n)*TT + t];
  }
  __syncthreads();

  const int o2 = tid & 63;
  const int j  = tid >> 6;
  float acc[16];
  float bias = fb[o2];
  #pragma unroll
  for (int i = 0; i < 16; ++i) acc[i] = bias;

  for (int half = 0; half < 2; ++half) {
    if (half) __syncthreads();     // prior compute finished reading z
    // gather + BN-normalize 128 channels
    for (int u = tid; u < 128 * 64; u += 256) {
      int cl = u >> 6;                 // 0..127
      int n  = u & 63;
      int c  = half * 128 + cl;        // global cat channel = t*64+o
      int t  = c >> 6, o = c & 63;
      int rn = rnl[t][n];
      float v = __bfloat162float(Y[(((size_t)(t*BB + b))*OO + o)*NN + rn]);
      z[cl][n] = v * ss[c*2 + 0] + ss[c*2 + 1];
    }
    __syncthreads();
    const float* fwh = fw + (size_t)o2 * 256 + half * 128;
    for (int cl = 0; cl < 128; ++cl) {
      float w = fwh[cl];
      const float* zr = &z[cl][j*16];   // wave-uniform -> broadcast
      #pragma unroll
      for (int i = 0; i < 16; ++i) acc[i] += w * zr[i];
    }
  }

  float s1 = 0.f, s2 = 0.f;
  #pragma unroll
  for (int i = 0; i < 16; ++i) { s1 += acc[i]; s2 += acc[i]*acc[i]; }
  __syncthreads();                 // all z reads done before stage reuse
  float (*stage)[66] = (float (*)[66])z;   // 64 x 66
  #pragma unroll
  for (int i = 0; i < 16; ++i) stage[o2][j*16 + i] = acc[i];
  sred[0][j][o2] = s1;
  sred[1][j][o2] = s2;
  __syncthreads();

  if (tid < 64) {
    float a = sred[0][0][tid] + sred[0][1][tid] + sred[0][2][tid] + sred[0][3][tid];
    float q = sred[1][0][tid] + sred[1][1][tid] + sred[1][2][tid] + sred[1][3][tid];
    atomicAdd(&fstats[tid*2 + 0], a);
    atomicAdd(&fstats[tid*2 + 1], q);
  }

  for (int u = tid; u < 64 * 64; u += 256) {
    int oo = u >> 6, n = u & 63;
    out[((size_t)(b*OO + oo))*NN + n0 + n] = stage[oo][n];
  }
}

// ---------------------------------------------------------------------------
// Kernel 4: fusion BN + relu, in place on d_out
// ---------------------------------------------------------------------------
__global__ __launch_bounds__(256) void final_kernel(
    float* __restrict__ out,
    const float* __restrict__ fstats,
    const float* __restrict__ fg,
    const float* __restrict__ fbeta)
{
  const int e0 = blockIdx.x * 2048 + threadIdx.x;
  const float inv = 1.f / (float)(BB * NN);
  #pragma unroll
  for (int s = 0; s < 8; ++s) {
    int e  = e0 + s * 256;           // grid sized so e < B*O*N exactly
    int o2 = (e >> 15) & 63;         // N = 2^15
    float s1 = fstats[o2*2 + 0];
    float s2 = fstats[o2*2 + 1];
    float mean = s1 * inv;
    float var  = s2 * inv - mean * mean;
    float sc = fg[o2] * rsqrtf(var + EPS_BN);
    float sh = fbeta[o2] - mean * sc;
    float v = out[e] * sc + sh;
    out[e] = fmaxf(v, 0.f);
  }
}

// ---------------------------------------------------------------------------
extern "C" void kernel_launch(void* const* d_in, const int* in_sizes, int n_in,
                              void* d_out, int out_size, void* d_ws, size_t ws_size,
                              hipStream_t stream) {
  const float* inp  = (const float*)d_in[0];
  const float* mc   = (const float*)d_in[1];
  const int*   ind  = (const int*)  d_in[2];
  const int*   rind = (const int*)  d_in[3];
  const float* cw   = (const float*)d_in[4];
  const float* bg   = (const float*)d_in[5];
  const float* bb   = (const float*)d_in[6];
  const float* fw   = (const float*)d_in[7];
  const float* fb   = (const float*)d_in[8];
  const float* fg   = (const float*)d_in[9];
  const float* fbt  = (const float*)d_in[10];

  char* ws = (char*)d_ws;
  float* cstats = (float*)(ws + 0);
  float* fstats = (float*)(ws + 2048);
  float* convss = (float*)(ws + 4096);
  __hip_bfloat16* Y = (__hip_bfloat16*)(ws + 8192);
  float* out = (float*)d_out;

  hipMemsetAsync(d_ws, 0, 8192, stream);   // zero stats accumulators

  dim3 g1(NN / TN, BB, TT);
  conv_kernel<<<g1, 256, 0, stream>>>(inp, mc, ind, cw, Y, cstats);

  bnparam_kernel<<<1, 256, 0, stream>>>(cstats, bg, bb, convss);

  dim3 g3(NN / 64, BB);
  fusion_kernel<<<g3, 256, 0, stream>>>(Y, rind, convss, fw, fb, out, fstats);

  final_kernel<<<(BB*OO*NN) / 2048, 256, 0, stream>>>(out, fstats, fg, fbt);
}

// Round 2
// 634.534 us; speedup vs baseline: 2.7402x; 2.7402x over previous
//
#include <hip/hip_runtime.h>
#include <hip/hip_bf16.h>

#define BB 4
#define CC 64
#define OO 64
#define NN 32768
#define TT 4
#define KK 9
#define PADW 4
#define SIGMA 0.05f
#define EPS_BN 1e-5f

typedef __attribute__((ext_vector_type(8))) short bf16x8;
typedef __attribute__((ext_vector_type(4))) float f32x4;

__device__ __forceinline__ unsigned short f2bf(float f) {
  __hip_bfloat16 h = __float2bfloat16(f);
  return *reinterpret_cast<unsigned short*>(&h);
}
__device__ __forceinline__ float bf2f(unsigned short u) {
  unsigned int x = ((unsigned int)u) << 16;
  float f;
  __builtin_memcpy(&f, &x, 4);
  return f;
}

// ---------------------------------------------------------------------------
// Prep 1: transpose input (B,C,N) f32 -> (B,N,C) bf16  (dense 128B per point)
// ---------------------------------------------------------------------------
__global__ __launch_bounds__(256) void transpose_kernel(
    const float* __restrict__ inp, unsigned short* __restrict__ xTb)
{
  const int n0 = blockIdx.x * 64;
  const int b  = blockIdx.y;
  const int tid = threadIdx.x;
  __shared__ float xt[64][65];
  {
    int nl = tid & 63, c4 = tid >> 6;
    #pragma unroll
    for (int i = 0; i < 16; ++i) {
      int c = c4 * 16 + i;
      xt[c][nl] = inp[((size_t)(b*CC + c))*NN + n0 + nl];
    }
  }
  __syncthreads();
  {
    int nl = tid >> 2, cq = tid & 3;
    unsigned int pk[8];
    #pragma unroll
    for (int i = 0; i < 8; ++i) {
      int c = cq*16 + i*2;
      unsigned int lo = f2bf(xt[c][nl]);
      unsigned int hi = f2bf(xt[c+1][nl]);
      pk[i] = lo | (hi << 16);
    }
    unsigned int* dst = (unsigned int*)(xTb + (((size_t)b*NN) + n0 + nl)*CC + cq*16);
    ((int4*)dst)[0] = make_int4((int)pk[0],(int)pk[1],(int)pk[2],(int)pk[3]);
    ((int4*)dst)[1] = make_int4((int)pk[4],(int)pk[5],(int)pk[6],(int)pk[7]);
  }
}

// ---------------------------------------------------------------------------
// Prep 2: conv weights (T,O,C,K) f32 -> (T,K,O,C) bf16
// ---------------------------------------------------------------------------
__global__ __launch_bounds__(256) void wprep_kernel(
    const float* __restrict__ cw, unsigned short* __restrict__ W2g)
{
  const int k = blockIdx.x;  // 0..8
  const int t = blockIdx.y;  // 0..3
  for (int u = threadIdx.x; u < OO*CC; u += 256) {
    int o = u >> 6, c = u & 63;
    float w = cw[(((size_t)(t*OO + o))*CC + c)*KK + k];
    W2g[(((size_t)(t*KK + k))*OO + o)*CC + c] = f2bf(w);
  }
}

// ---------------------------------------------------------------------------
// Kernel: MFMA weighted conv.  Per block: (n-tile 64, b, t).
//   out[o,nl] = sum_k wgt[nl,k] * (W_k . xg)[o, nl+k]
// ---------------------------------------------------------------------------
__global__ __launch_bounds__(256) void conv_kernel(
    const unsigned short* __restrict__ xTb,  // (B,N,C) bf16
    const float* __restrict__ mc,            // (B,3,N,T)
    const int*   __restrict__ ind,           // (B,N,T)
    const unsigned short* __restrict__ W2g,  // (T,K,O,C) bf16
    unsigned short* __restrict__ Y,          // (B,N,T,O) bf16
    float* __restrict__ cstats)              // (T*O,2)
{
  const int n0  = blockIdx.x * 64;
  const int b   = blockIdx.y;
  const int t   = blockIdx.z;
  const int tid = threadIdx.x;
  const int lane = tid & 63;
  const int wv   = tid >> 6;

  __shared__ short xg[72][72];        // gathered window, [point][c], bf16 bits
  __shared__ float wgl[64][KK+1];     // stride 10 -> conflict-free column reads
  __shared__ float stage[64][66];     // fp32 out staging
  __shared__ float sred[2][4][64];

  // gather: 72 points x 8 chunks of 16B
  for (int u = tid; u < 72*8; u += 256) {
    int p = u >> 3, s = u & 7;
    int m = n0 + p - PADW;
    int4 v = make_int4(0,0,0,0);
    if (m >= 0 && m < NN) {
      int idx = ind[((size_t)b*NN + m)*TT + t];
      v = *(const int4*)(xTb + ((size_t)b*NN + idx)*CC + s*8);
    }
    *(int4*)&xg[p][s*8] = v;
  }

  // window weights wgt[nl][k]  (ref pads coords with zeros at OOB)
  for (int u = tid; u < 576; u += 256) {
    int k = u >> 6, nl = u & 63;
    int n = n0 + nl;
    int m = n + k - PADW;
    float cx = mc[(((size_t)(b*3+0))*NN + n)*TT + t];
    float cy = mc[(((size_t)(b*3+1))*NN + n)*TT + t];
    float cz = mc[(((size_t)(b*3+2))*NN + n)*TT + t];
    float px = 0.f, py = 0.f, pz = 0.f;
    if (m >= 0 && m < NN) {
      px = mc[(((size_t)(b*3+0))*NN + m)*TT + t];
      py = mc[(((size_t)(b*3+1))*NN + m)*TT + t];
      pz = mc[(((size_t)(b*3+2))*NN + m)*TT + t];
    }
    float dx = px-cx, dy = py-cy, dz = pz-cz;
    float s2 = dx*dx + dy*dy + dz*dz;
    float r = (s2 > 0.f) ? sqrtf(s2) : 0.f;
    wgl[nl][k] = fmaxf(1.f - r*(1.f/SIGMA), 0.f);
  }
  __syncthreads();

  const int q   = lane >> 4;
  const int nlo = wv*16 + (lane & 15);     // this lane's n column
  const unsigned short* Wt = W2g + (size_t)t*KK*OO*CC;

  float fin[4][4];
  #pragma unroll
  for (int i = 0; i < 4; ++i)
    #pragma unroll
    for (int j = 0; j < 4; ++j) fin[i][j] = 0.f;

  for (int k = 0; k < KK; ++k) {
    bf16x8 bf0 = *(const bf16x8*)&xg[nlo + k][q*8];
    bf16x8 bf1 = *(const bf16x8*)&xg[nlo + k][32 + q*8];
    float wgtl = wgl[nlo][k];
    const unsigned short* Wk = Wt + (size_t)k*OO*CC;
    #pragma unroll
    for (int ot = 0; ot < 4; ++ot) {
      const unsigned short* wp = Wk + (size_t)(ot*16 + (lane & 15))*CC + q*8;
      bf16x8 af0 = *(const bf16x8*)(wp);
      bf16x8 af1 = *(const bf16x8*)(wp + 32);
      f32x4 d = {0.f, 0.f, 0.f, 0.f};
      d = __builtin_amdgcn_mfma_f32_16x16x32_bf16(af0, bf0, d, 0, 0, 0);
      d = __builtin_amdgcn_mfma_f32_16x16x32_bf16(af1, bf1, d, 0, 0, 0);
      #pragma unroll
      for (int r = 0; r < 4; ++r) fin[ot][r] += wgtl * d[r];
    }
  }

  // D layout: col = lane&15 (=nlo within wave tile), row = q*4 + r
  #pragma unroll
  for (int ot = 0; ot < 4; ++ot)
    #pragma unroll
    for (int r = 0; r < 4; ++r)
      stage[ot*16 + q*4 + r][nlo] = fin[ot][r];
  __syncthreads();

  // per-(t,o) stats
  {
    int o = tid & 63, j = tid >> 6;
    float s1 = 0.f, s2 = 0.f;
    #pragma unroll
    for (int i = 0; i < 16; ++i) {
      float v = stage[o][j*16 + i];
      s1 += v; s2 += v*v;
    }
    sred[0][j][o] = s1;
    sred[1][j][o] = s2;
  }
  __syncthreads();
  if (tid < 64) {
    float a  = sred[0][0][tid]+sred[0][1][tid]+sred[0][2][tid]+sred[0][3][tid];
    float qq = sred[1][0][tid]+sred[1][1][tid]+sred[1][2][tid]+sred[1][3][tid];
    atomicAdd(&cstats[(t*OO + tid)*2 + 0], a);
    atomicAdd(&cstats[(t*OO + tid)*2 + 1], qq);
  }

  // Y store, layout (B,N,T,O): each thread packs 16 o's (32B) for one point
  {
    int g = tid >> 6, n = tid & 63;
    unsigned int pk[8];
    #pragma unroll
    for (int i = 0; i < 8; ++i) {
      unsigned int lo = f2bf(stage[g*16 + 2*i    ][n]);
      unsigned int hi = f2bf(stage[g*16 + 2*i + 1][n]);
      pk[i] = lo | (hi << 16);
    }
    unsigned int* dst = (unsigned int*)(Y + (((size_t)b*NN + n0 + n)*TT + t)*OO + g*16);
    ((int4*)dst)[0] = make_int4((int)pk[0],(int)pk[1],(int)pk[2],(int)pk[3]);
    ((int4*)dst)[1] = make_int4((int)pk[4],(int)pk[5],(int)pk[6],(int)pk[7]);
  }
}

// ---------------------------------------------------------------------------
// fold conv BN stats into per-(t,o) scale/shift
// ---------------------------------------------------------------------------
__global__ void bnparam_kernel(const float* __restrict__ cstats,
                               const float* __restrict__ gam,
                               const float* __restrict__ bet,
                               float* __restrict__ ss)
{
  int tid = threadIdx.x;   // 256 = T*O
  float s1 = cstats[tid*2 + 0];
  float s2 = cstats[tid*2 + 1];
  const float inv = 1.f / (float)(BB * NN);
  float mean = s1 * inv;
  float var  = s2 * inv - mean * mean;
  float sc = gam[tid] * rsqrtf(var + EPS_BN);
  ss[tid*2 + 0] = sc;
  ss[tid*2 + 1] = bet[tid] - mean * sc;
}

// ---------------------------------------------------------------------------
// Fusion: reindex gather (dense 128B) + inline BN -> zg, then K=256 MFMA GEMM
// ---------------------------------------------------------------------------
__global__ __launch_bounds__(256) void fusion_kernel(
    const unsigned short* __restrict__ Y,   // (B,N,T,O) bf16
    const int*   __restrict__ rind,         // (B,N,T)
    const float* __restrict__ ss,           // (T*O,2)
    const float* __restrict__ fw,           // (O,256) f32
    const float* __restrict__ fb,           // (O)
    float* __restrict__ out,                // (B,O,N)
    float* __restrict__ fstats)             // (O,2)
{
  const int n0  = blockIdx.x * 64;
  const int b   = blockIdx.y;
  const int tid = threadIdx.x;
  const int lane = tid & 63, wv = tid >> 6;

  __shared__ short zg[64][264];     // [n][c'] bf16 bits, stride 264 (16B-aligned rows)
  __shared__ int   rnl[TT][64];
  __shared__ float sred[2][4][64];

  {
    int tt = tid >> 6, n = tid & 63;
    rnl[tt][n] = rind[((size_t)b*NN + n0 + n)*TT + tt];
  }
  __syncthreads();

  // stage: 64 n x 4 t x 8 chunks(16B), BN affine applied inline
  for (int u = tid; u < 2048; u += 256) {
    int n = u >> 5, tt = (u >> 3) & 3, s = u & 7;
    int rn = rnl[tt][n];
    int4 raw = *(const int4*)(Y + (((size_t)b*NN + rn)*TT + tt)*OO + s*8);
    const unsigned short* rp = (const unsigned short*)&raw;
    int cbase = tt*64 + s*8;
    unsigned int pk[4];
    #pragma unroll
    for (int i = 0; i < 4; ++i) {
      float v0 = bf2f(rp[2*i  ]) * ss[(cbase+2*i  )*2] + ss[(cbase+2*i  )*2+1];
      float v1 = bf2f(rp[2*i+1]) * ss[(cbase+2*i+1)*2] + ss[(cbase+2*i+1)*2+1];
      pk[i] = (unsigned int)f2bf(v0) | ((unsigned int)f2bf(v1) << 16);
    }
    *(int4*)&zg[n][tt*64 + s*8] = make_int4((int)pk[0],(int)pk[1],(int)pk[2],(int)pk[3]);
  }
  __syncthreads();

  const int q   = lane >> 4;
  const int nlo = wv*16 + (lane & 15);

  f32x4 acc4[4];
  #pragma unroll
  for (int i = 0; i < 4; ++i) acc4[i] = (f32x4){0.f,0.f,0.f,0.f};

  #pragma unroll
  for (int kk = 0; kk < 8; ++kk) {
    bf16x8 bf = *(const bf16x8*)&zg[nlo][kk*32 + q*8];
    #pragma unroll
    for (int ot = 0; ot < 4; ++ot) {
      const float* wp = fw + (size_t)(ot*16 + (lane & 15))*256 + kk*32 + q*8;
      float4 wa = *(const float4*)wp;
      float4 wb = *(const float4*)(wp + 4);
      bf16x8 af;
      af[0] = (short)f2bf(wa.x); af[1] = (short)f2bf(wa.y);
      af[2] = (short)f2bf(wa.z); af[3] = (short)f2bf(wa.w);
      af[4] = (short)f2bf(wb.x); af[5] = (short)f2bf(wb.y);
      af[6] = (short)f2bf(wb.z); af[7] = (short)f2bf(wb.w);
      acc4[ot] = __builtin_amdgcn_mfma_f32_16x16x32_bf16(af, bf, acc4[ot], 0, 0, 0);
    }
  }
  __syncthreads();   // all zg reads complete before reuse as stage

  float (*stage)[66] = (float (*)[66])&zg[0][0];
  #pragma unroll
  for (int ot = 0; ot < 4; ++ot)
    #pragma unroll
    for (int r = 0; r < 4; ++r) {
      int o = ot*16 + q*4 + r;
      stage[o][nlo] = acc4[ot][r] + fb[o];
    }
  __syncthreads();

  {
    int o = tid & 63, j = tid >> 6;
    float s1 = 0.f, s2 = 0.f;
    #pragma unroll
    for (int i = 0; i < 16; ++i) {
      float v = stage[o][j*16 + i];
      s1 += v; s2 += v*v;
    }
    sred[0][j][o] = s1;
    sred[1][j][o] = s2;
  }
  __syncthreads();
  if (tid < 64) {
    float a  = sred[0][0][tid]+sred[0][1][tid]+sred[0][2][tid]+sred[0][3][tid];
    float qq = sred[1][0][tid]+sred[1][1][tid]+sred[1][2][tid]+sred[1][3][tid];
    atomicAdd(&fstats[tid*2 + 0], a);
    atomicAdd(&fstats[tid*2 + 1], qq);
  }

  for (int u = tid; u < 4096; u += 256) {
    int oo = u >> 6, n = u & 63;
    out[((size_t)(b*OO + oo))*NN + n0 + n] = stage[oo][n];
  }
}

// ---------------------------------------------------------------------------
// fusion BN + relu, in place
// ---------------------------------------------------------------------------
__global__ __launch_bounds__(256) void final_kernel(
    float* __restrict__ out,
    const float* __restrict__ fstats,
    const float* __restrict__ fg,
    const float* __restrict__ fbeta)
{
  const int e0 = blockIdx.x * 2048 + threadIdx.x;
  const float inv = 1.f / (float)(BB * NN);
  #pragma unroll
  for (int s = 0; s < 8; ++s) {
    int e  = e0 + s * 256;
    int o2 = (e >> 15) & 63;
    float s1 = fstats[o2*2 + 0];
    float s2 = fstats[o2*2 + 1];
    float mean = s1 * inv;
    float var  = s2 * inv - mean * mean;
    float sc = fg[o2] * rsqrtf(var + EPS_BN);
    float sh = fbeta[o2] - mean * sc;
    float v = out[e] * sc + sh;
    out[e] = fmaxf(v, 0.f);
  }
}

// ---------------------------------------------------------------------------
extern "C" void kernel_launch(void* const* d_in, const int* in_sizes, int n_in,
                              void* d_out, int out_size, void* d_ws, size_t ws_size,
                              hipStream_t stream) {
  const float* inp  = (const float*)d_in[0];
  const float* mc   = (const float*)d_in[1];
  const int*   ind  = (const int*)  d_in[2];
  const int*   rind = (const int*)  d_in[3];
  const float* cw   = (const float*)d_in[4];
  const float* bg   = (const float*)d_in[5];
  const float* bb   = (const float*)d_in[6];
  const float* fw   = (const float*)d_in[7];
  const float* fb   = (const float*)d_in[8];
  const float* fg   = (const float*)d_in[9];
  const float* fbt  = (const float*)d_in[10];

  // ws (footprint identical to round 1: 67,117,056 B):
  char* ws = (char*)d_ws;
  float* cstats = (float*)(ws + 0);       // 2048 B
  float* fstats = (float*)(ws + 2048);    // 512 B
  float* convss = (float*)(ws + 4096);    // 2048 B
  unsigned short* Y = (unsigned short*)(ws + 8192);   // (B,N,T,O) bf16, 64 MiB

  // scratch inside d_out (dead before fusion writes d_out):
  char* ob = (char*)d_out;
  unsigned short* xTb = (unsigned short*)ob;               // 16,777,216 B
  unsigned short* W2g = (unsigned short*)(ob + 16777216);  // 294,912 B
  float* out = (float*)d_out;

  hipMemsetAsync(d_ws, 0, 8192, stream);   // zero stats accumulators

  dim3 gt(NN/64, BB);
  transpose_kernel<<<gt, 256, 0, stream>>>(inp, xTb);

  dim3 gw(KK, TT);
  wprep_kernel<<<gw, 256, 0, stream>>>(cw, W2g);

  dim3 gc(NN/64, BB, TT);
  conv_kernel<<<gc, 256, 0, stream>>>(xTb, mc, ind, W2g, Y, cstats);

  bnparam_kernel<<<1, 256, 0, stream>>>(cstats, bg, bb, convss);

  dim3 gf(NN/64, BB);
  fusion_kernel<<<gf, 256, 0, stream>>>(Y, rind, convss, fw, fb, out, fstats);

  final_kernel<<<(BB*OO*NN)/2048, 256, 0, stream>>>(out, fstats, fg, fbt);
}

// Round 3
// 423.209 us; speedup vs baseline: 4.1085x; 1.4993x over previous
//
#include <hip/hip_runtime.h>
#include <hip/hip_bf16.h>

#define BB 4
#define CC 64
#define OO 64
#define NN 32768
#define TT 4
#define KK 9
#define PADW 4
#define SIGMA 0.05f
#define EPS_BN 1e-5f

typedef __attribute__((ext_vector_type(8))) short bf16x8;
typedef __attribute__((ext_vector_type(4))) float f32x4;

__device__ __forceinline__ unsigned short f2bf(float f) {
  __hip_bfloat16 h = __float2bfloat16(f);
  return *reinterpret_cast<unsigned short*>(&h);
}
__device__ __forceinline__ float bf2f(unsigned short u) {
  unsigned int x = ((unsigned int)u) << 16;
  float f;
  __builtin_memcpy(&f, &x, 4);
  return f;
}
__device__ __forceinline__ unsigned int pkbf(float a, float b) {
  float2 t; t.x = a; t.y = b;
  __hip_bfloat162 h = __float22bfloat162_rn(t);
  unsigned int r;
  __builtin_memcpy(&r, &h, 4);
  return r;
}

// ---------------------------------------------------------------------------
// Prep 1: transpose input (B,C,N) f32 -> (B,N,C) bf16
// ---------------------------------------------------------------------------
__global__ __launch_bounds__(256) void transpose_kernel(
    const float* __restrict__ inp, unsigned short* __restrict__ xTb)
{
  const int n0 = blockIdx.x * 64;
  const int b  = blockIdx.y;
  const int tid = threadIdx.x;
  __shared__ float xt[64][65];
  {
    int nl = tid & 63, c4 = tid >> 6;
    #pragma unroll
    for (int i = 0; i < 16; ++i) {
      int c = c4 * 16 + i;
      xt[c][nl] = inp[((size_t)(b*CC + c))*NN + n0 + nl];
    }
  }
  __syncthreads();
  {
    int nl = tid >> 2, cq = tid & 3;
    unsigned int pk[8];
    #pragma unroll
    for (int i = 0; i < 8; ++i) {
      int c = cq*16 + i*2;
      pk[i] = pkbf(xt[c][nl], xt[c+1][nl]);
    }
    unsigned int* dst = (unsigned int*)(xTb + (((size_t)b*NN) + n0 + nl)*CC + cq*16);
    ((int4*)dst)[0] = make_int4((int)pk[0],(int)pk[1],(int)pk[2],(int)pk[3]);
    ((int4*)dst)[1] = make_int4((int)pk[4],(int)pk[5],(int)pk[6],(int)pk[7]);
  }
}

// ---------------------------------------------------------------------------
// Prep 2: conv weights (T,O,C,K) f32 -> (T,O,576) bf16, col = k*64 + c
// ---------------------------------------------------------------------------
__global__ __launch_bounds__(256) void wprep_kernel(
    const float* __restrict__ cw, unsigned short* __restrict__ W3)
{
  const int k = blockIdx.x;  // 0..8
  const int t = blockIdx.y;  // 0..3
  for (int u = threadIdx.x; u < OO*CC; u += 256) {
    int o = u >> 6, c = u & 63;
    float w = cw[(((size_t)(t*OO + o))*CC + c)*KK + k];
    W3[((size_t)(t*OO + o))*576 + k*64 + c] = f2bf(w);
  }
}

// ---------------------------------------------------------------------------
// Conv: n-tile 128, waves 2x2 (32o x 64n each), full C-resident accumulation.
//   fin[o,n] = sum_k wgt[n,k] * (W_k . xgathered)[o, n+k]
// ---------------------------------------------------------------------------
__global__ __launch_bounds__(256, 4) void conv_kernel(
    const unsigned short* __restrict__ xTb,  // (B,N,C) bf16
    const float* __restrict__ mc,            // (B,3,N,T)
    const int*   __restrict__ ind,           // (B,N,T)
    const unsigned short* __restrict__ W3,   // (T,O,576) bf16
    unsigned short* __restrict__ Y,          // (B,N,T,O) bf16
    float* __restrict__ cstats)              // (T*O,2)
{
  const int n0  = blockIdx.x * 128;
  const int b   = blockIdx.y;
  const int t   = blockIdx.z;
  const int tid = threadIdx.x;
  const int lane = tid & 63;
  const int w    = tid >> 6;
  const int l15  = lane & 15;
  const int q    = lane >> 4;
  const int ow   = w & 1;     // o half  (32 o's)
  const int nw   = w >> 1;    // n half  (64 n's)

  // union region: {xg[136][72] shorts + wgl[128][10] f32 + cxyz[3][128] f32}
  //            vs {stage float[128][68]}
  __shared__ __align__(16) char U[34816];
  __shared__ float sred[2][4][64];
  short* xg   = (short*)U;                    // [136][72]
  float* wgl  = (float*)(U + 19584);          // [128][10]
  float* cxyz = (float*)(U + 19584 + 5120);   // [3][128]
  float* stage = (float*)U;                   // [128][68]

  // phase 1: center coords + gather
  for (int u = tid; u < 384; u += 256) {
    int d = u >> 7, nl = u & 127;
    cxyz[d*128 + nl] = mc[(((size_t)(b*3+d))*NN + n0 + nl)*TT + t];
  }
  for (int u = tid; u < 1088; u += 256) {
    int p = u >> 3, s = u & 7;
    int m = n0 + p - PADW;
    int4 v = make_int4(0,0,0,0);
    if (m >= 0 && m < NN) {
      int idx = ind[((size_t)b*NN + m)*TT + t];
      v = *(const int4*)(xTb + ((size_t)b*NN + idx)*CC + s*8);
    }
    *(int4*)&xg[p*72 + s*8] = v;
  }
  __syncthreads();

  // phase 2: window weights
  for (int u = tid; u < 1152; u += 256) {
    int k = u >> 7, nl = u & 127;
    int m = n0 + nl + k - PADW;
    float px = 0.f, py = 0.f, pz = 0.f;
    if (m >= 0 && m < NN) {
      px = mc[(((size_t)(b*3+0))*NN + m)*TT + t];
      py = mc[(((size_t)(b*3+1))*NN + m)*TT + t];
      pz = mc[(((size_t)(b*3+2))*NN + m)*TT + t];
    }
    float dx = px - cxyz[0*128+nl];
    float dy = py - cxyz[1*128+nl];
    float dz = pz - cxyz[2*128+nl];
    float s2 = dx*dx + dy*dy + dz*dz;
    float r = (s2 > 0.f) ? sqrtf(s2) : 0.f;
    wgl[nl*10 + k] = fmaxf(1.f - r*(1.f/SIGMA), 0.f);
  }
  __syncthreads();

  // phase 3: MFMA compute
  const unsigned short* Wbase = W3 + (size_t)t*OO*576;
  const f32x4 Z = {0.f, 0.f, 0.f, 0.f};
  f32x4 fin[2][4];
  #pragma unroll
  for (int ot = 0; ot < 2; ++ot)
    #pragma unroll
    for (int ns = 0; ns < 4; ++ns) fin[ot][ns] = Z;

  for (int k = 0; k < KK; ++k) {
    bf16x8 af[2][2];
    #pragma unroll
    for (int ot = 0; ot < 2; ++ot) {
      const unsigned short* ap =
          Wbase + (size_t)(ow*32 + ot*16 + l15)*576 + k*64 + q*8;
      af[ot][0] = *(const bf16x8*)(ap);
      af[ot][1] = *(const bf16x8*)(ap + 32);
    }
    #pragma unroll
    for (int ns = 0; ns < 4; ++ns) {
      int nl = nw*64 + ns*16 + l15;
      int p  = nl + k;
      bf16x8 b0 = *(const bf16x8*)&xg[p*72 + q*8];
      bf16x8 b1 = *(const bf16x8*)&xg[p*72 + 32 + q*8];
      float wgt = wgl[nl*10 + k];
      #pragma unroll
      for (int ot = 0; ot < 2; ++ot) {
        f32x4 d = __builtin_amdgcn_mfma_f32_16x16x32_bf16(af[ot][0], b0, Z, 0, 0, 0);
        d = __builtin_amdgcn_mfma_f32_16x16x32_bf16(af[ot][1], b1, d, 0, 0, 0);
        fin[ot][ns] += wgt * d;
      }
    }
  }
  __syncthreads();   // xg/wgl dead, reuse as stage

  // epilogue: stage[n][o] fp32, stride 68
  #pragma unroll
  for (int ot = 0; ot < 2; ++ot)
    #pragma unroll
    for (int ns = 0; ns < 4; ++ns) {
      int nl = nw*64 + ns*16 + l15;
      *(f32x4*)&stage[nl*68 + ow*32 + ot*16 + q*4] = fin[ot][ns];
    }
  __syncthreads();

  // per-(t,o) stats
  {
    int o = tid & 63, j = tid >> 6;
    float s1 = 0.f, s2 = 0.f;
    #pragma unroll
    for (int i = 0; i < 32; ++i) {
      float v = stage[(j*32 + i)*68 + o];
      s1 += v; s2 += v*v;
    }
    sred[0][j][o] = s1;
    sred[1][j][o] = s2;
  }
  __syncthreads();
  if (tid < 64) {
    float a  = sred[0][0][tid]+sred[0][1][tid]+sred[0][2][tid]+sred[0][3][tid];
    float qq = sred[1][0][tid]+sred[1][1][tid]+sred[1][2][tid]+sred[1][3][tid];
    atomicAdd(&cstats[(t*OO + tid)*2 + 0], a);
    atomicAdd(&cstats[(t*OO + tid)*2 + 1], qq);
  }

  // Y store (B,N,T,O): thread -> (n = tid>>1, o-half = tid&1), 64 B each
  {
    int n = tid >> 1, h = tid & 1;
    const float* src = stage + n*68 + h*32;
    int4 st[4];
    #pragma unroll
    for (int j = 0; j < 4; ++j) {
      float4 a  = *(const float4*)(src + j*8);
      float4 b2 = *(const float4*)(src + j*8 + 4);
      st[j] = make_int4((int)pkbf(a.x,a.y), (int)pkbf(a.z,a.w),
                        (int)pkbf(b2.x,b2.y), (int)pkbf(b2.z,b2.w));
    }
    int4* dst = (int4*)(Y + (((size_t)b*NN + n0 + n)*TT + t)*OO + h*32);
    #pragma unroll
    for (int j = 0; j < 4; ++j) dst[j] = st[j];
  }
}

// ---------------------------------------------------------------------------
// fold conv BN stats into per-(t,o) scale/shift
// ---------------------------------------------------------------------------
__global__ void bnparam_kernel(const float* __restrict__ cstats,
                               const float* __restrict__ gam,
                               const float* __restrict__ bet,
                               float* __restrict__ ss)
{
  int tid = threadIdx.x;   // 256 = T*O
  float s1 = cstats[tid*2 + 0];
  float s2 = cstats[tid*2 + 1];
  const float inv = 1.f / (float)(BB * NN);
  float mean = s1 * inv;
  float var  = s2 * inv - mean * mean;
  float sc = gam[tid] * rsqrtf(var + EPS_BN);
  ss[tid*2 + 0] = sc;
  ss[tid*2 + 1] = bet[tid] - mean * sc;
}

// ---------------------------------------------------------------------------
// Fusion: n-tile 128, K=256 in two staged halves, C-resident accumulation.
// ---------------------------------------------------------------------------
__global__ __launch_bounds__(256, 4) void fusion_kernel(
    const unsigned short* __restrict__ Y,   // (B,N,T,O) bf16
    const int*   __restrict__ rind,         // (B,N,T)
    const float* __restrict__ ss,           // (T*O,2)
    const float* __restrict__ fw,           // (O,256) f32
    const float* __restrict__ fb,           // (O)
    float* __restrict__ out,                // (B,O,N) pre-BN
    float* __restrict__ fstats)             // (O,2)
{
  const int n0  = blockIdx.x * 128;
  const int b   = blockIdx.y;
  const int tid = threadIdx.x;
  const int lane = tid & 63;
  const int w    = tid >> 6;
  const int l15  = lane & 15;
  const int q    = lane >> 4;
  const int ow   = w & 1;
  const int nw   = w >> 1;

  // union: zg short[128][136] (34816 B)  vs  stage float[64][132] (33792 B)
  __shared__ __align__(16) char U[34816];
  __shared__ float sred[2][4][64];
  __shared__ int   rnl[TT][128];
  __shared__ float ssl[512];
  short* zg = (short*)U;
  float* stage = (float*)U;

  for (int u = tid; u < 512; u += 256) {
    int tt = u >> 7, nl = u & 127;
    rnl[tt][nl] = rind[((size_t)b*NN + n0 + nl)*TT + tt];
    ssl[u] = ss[u];
    ssl[u + 256] = ss[u + 256];
  }
  // note: ssl[0..511] loaded (u and u+256 over u in [0,512) covers 0..767 — fix below)
  __syncthreads();

  const f32x4 Z = {0.f,0.f,0.f,0.f};
  f32x4 fin[2][4];
  #pragma unroll
  for (int ot = 0; ot < 2; ++ot)
    #pragma unroll
    for (int ns = 0; ns < 4; ++ns) fin[ot][ns] = Z;

  for (int h = 0; h < 2; ++h) {
    if (h) __syncthreads();    // previous compute done reading zg
    // stage half: tt in {2h, 2h+1}
    for (int u = tid; u < 2048; u += 256) {
      int n = u >> 4, tl = (u >> 3) & 1, s = u & 7;
      int tt = h*2 + tl;
      int rn = rnl[tt][n];
      int4 raw = *(const int4*)(Y + (((size_t)b*NN + rn)*TT + tt)*OO + s*8);
      const unsigned short* rp = (const unsigned short*)&raw;
      int cb = tt*64 + s*8;
      unsigned int pk[4];
      #pragma unroll
      for (int i = 0; i < 4; ++i) {
        float v0 = bf2f(rp[2*i  ]) * ssl[(cb+2*i  )*2] + ssl[(cb+2*i  )*2+1];
        float v1 = bf2f(rp[2*i+1]) * ssl[(cb+2*i+1)*2] + ssl[(cb+2*i+1)*2+1];
        pk[i] = pkbf(v0, v1);
      }
      *(int4*)&zg[n*136 + tl*64 + s*8] =
          make_int4((int)pk[0],(int)pk[1],(int)pk[2],(int)pk[3]);
    }
    __syncthreads();

    #pragma unroll
    for (int kk = 0; kk < 4; ++kk) {
      bf16x8 af[2];
      #pragma unroll
      for (int ot = 0; ot < 2; ++ot) {
        const float* wp = fw + (size_t)(ow*32 + ot*16 + l15)*256 + h*128 + kk*32 + q*8;
        float4 wa = *(const float4*)wp;
        float4 wb = *(const float4*)(wp + 4);
        unsigned int u0 = pkbf(wa.x, wa.y), u1 = pkbf(wa.z, wa.w);
        unsigned int u2 = pkbf(wb.x, wb.y), u3 = pkbf(wb.z, wb.w);
        int4 tmp = make_int4((int)u0,(int)u1,(int)u2,(int)u3);
        __builtin_memcpy(&af[ot], &tmp, 16);
      }
      #pragma unroll
      for (int ns = 0; ns < 4; ++ns) {
        int nl = nw*64 + ns*16 + l15;
        bf16x8 bfr = *(const bf16x8*)&zg[nl*136 + kk*32 + q*8];
        #pragma unroll
        for (int ot = 0; ot < 2; ++ot)
          fin[ot][ns] = __builtin_amdgcn_mfma_f32_16x16x32_bf16(af[ot], bfr, fin[ot][ns], 0, 0, 0);
      }
    }
  }
  __syncthreads();   // zg dead, reuse as stage

  // epilogue: stage[o][n] stride 132, add bias
  #pragma unroll
  for (int ot = 0; ot < 2; ++ot) {
    #pragma unroll
    for (int r = 0; r < 4; ++r) {
      int o = ow*32 + ot*16 + q*4 + r;
      float bias = fb[o];
      #pragma unroll
      for (int ns = 0; ns < 4; ++ns) {
        int nl = nw*64 + ns*16 + l15;
        stage[o*132 + nl] = fin[ot][ns][r] + bias;
      }
    }
  }
  __syncthreads();

  {
    int o = tid & 63, j = tid >> 6;
    const float* src = stage + o*132 + j*32;
    float s1 = 0.f, s2 = 0.f;
    #pragma unroll
    for (int i = 0; i < 8; ++i) {
      float4 v = ((const float4*)src)[i];
      s1 += v.x + v.y + v.z + v.w;
      s2 += v.x*v.x + v.y*v.y + v.z*v.z + v.w*v.w;
    }
    sred[0][j][o] = s1;
    sred[1][j][o] = s2;
  }
  __syncthreads();
  if (tid < 64) {
    float a  = sred[0][0][tid]+sred[0][1][tid]+sred[0][2][tid]+sred[0][3][tid];
    float qq = sred[1][0][tid]+sred[1][1][tid]+sred[1][2][tid]+sred[1][3][tid];
    atomicAdd(&fstats[tid*2 + 0], a);
    atomicAdd(&fstats[tid*2 + 1], qq);
  }

  {
    int o = tid >> 2, jj = tid & 3;
    const float* src = stage + o*132 + jj*32;
    float* dst = out + ((size_t)(b*OO + o))*NN + n0 + jj*32;
    #pragma unroll
    for (int i = 0; i < 8; ++i) ((float4*)dst)[i] = ((const float4*)src)[i];
  }
}

// ---------------------------------------------------------------------------
// fusion BN + relu, in place
// ---------------------------------------------------------------------------
__global__ __launch_bounds__(256) void final_kernel(
    float* __restrict__ out,
    const float* __restrict__ fstats,
    const float* __restrict__ fg,
    const float* __restrict__ fbeta)
{
  const int e0 = blockIdx.x * 2048 + threadIdx.x;
  const float inv = 1.f / (float)(BB * NN);
  #pragma unroll
  for (int s = 0; s < 8; ++s) {
    int e  = e0 + s * 256;
    int o2 = (e >> 15) & 63;
    float s1 = fstats[o2*2 + 0];
    float s2 = fstats[o2*2 + 1];
    float mean = s1 * inv;
    float var  = s2 * inv - mean * mean;
    float sc = fg[o2] * rsqrtf(var + EPS_BN);
    float sh = fbeta[o2] - mean * sc;
    float v = out[e] * sc + sh;
    out[e] = fmaxf(v, 0.f);
  }
}

// ---------------------------------------------------------------------------
extern "C" void kernel_launch(void* const* d_in, const int* in_sizes, int n_in,
                              void* d_out, int out_size, void* d_ws, size_t ws_size,
                              hipStream_t stream) {
  const float* inp  = (const float*)d_in[0];
  const float* mc   = (const float*)d_in[1];
  const int*   ind  = (const int*)  d_in[2];
  const int*   rind = (const int*)  d_in[3];
  const float* cw   = (const float*)d_in[4];
  const float* bg   = (const float*)d_in[5];
  const float* bb   = (const float*)d_in[6];
  const float* fw   = (const float*)d_in[7];
  const float* fb   = (const float*)d_in[8];
  const float* fg   = (const float*)d_in[9];
  const float* fbt  = (const float*)d_in[10];

  // ws: [0,2048) cstats | [2048,2560) fstats | [4096,6144) convss | [8192,+64MiB) Y
  char* ws = (char*)d_ws;
  float* cstats = (float*)(ws + 0);
  float* fstats = (float*)(ws + 2048);
  float* convss = (float*)(ws + 4096);
  unsigned short* Y = (unsigned short*)(ws + 8192);

  // scratch in d_out (dead before fusion writes it):
  char* ob = (char*)d_out;
  unsigned short* xTb = (unsigned short*)ob;               // 16,777,216 B
  unsigned short* W3  = (unsigned short*)(ob + 16777216);  // 294,912 B
  float* out = (float*)d_out;

  hipMemsetAsync(d_ws, 0, 8192, stream);

  dim3 gt(NN/64, BB);
  transpose_kernel<<<gt, 256, 0, stream>>>(inp, xTb);

  dim3 gw(KK, TT);
  wprep_kernel<<<gw, 256, 0, stream>>>(cw, W3);

  dim3 gc(NN/128, BB, TT);
  conv_kernel<<<gc, 256, 0, stream>>>(xTb, mc, ind, W3, Y, cstats);

  bnparam_kernel<<<1, 256, 0, stream>>>(cstats, bg, bb, convss);

  dim3 gf(NN/128, BB);
  fusion_kernel<<<gf, 256, 0, stream>>>(Y, rind, convss, fw, fb, out, fstats);

  final_kernel<<<(BB*OO*NN)/2048, 256, 0, stream>>>(out, fstats, fg, fbt);
}

// Round 4
// 283.974 us; speedup vs baseline: 6.1230x; 1.4903x over previous
//
#include <hip/hip_runtime.h>
#include <hip/hip_bf16.h>

#define BB 4
#define CC 64
#define OO 64
#define NN 32768
#define TT 4
#define KK 9
#define PADW 4
#define SIGMA 0.05f
#define EPS_BN 1e-5f

typedef __attribute__((ext_vector_type(8))) short bf16x8;
typedef __attribute__((ext_vector_type(4))) float f32x4;

__device__ __forceinline__ unsigned short f2bf(float f) {
  __hip_bfloat16 h = __float2bfloat16(f);
  return *reinterpret_cast<unsigned short*>(&h);
}
__device__ __forceinline__ float bf2f(unsigned short u) {
  unsigned int x = ((unsigned int)u) << 16;
  float f;
  __builtin_memcpy(&f, &x, 4);
  return f;
}
__device__ __forceinline__ unsigned int pkbf(float a, float b) {
  float2 t; t.x = a; t.y = b;
  __hip_bfloat162 h = __float22bfloat162_rn(t);
  unsigned int r;
  __builtin_memcpy(&r, &h, 4);
  return r;
}

// ---------------------------------------------------------------------------
// Prep 1: transpose input (B,C,N) f32 -> (B,N,C) bf16
// ---------------------------------------------------------------------------
__global__ __launch_bounds__(256) void transpose_kernel(
    const float* __restrict__ inp, unsigned short* __restrict__ xTb)
{
  const int n0 = blockIdx.x * 64;
  const int b  = blockIdx.y;
  const int tid = threadIdx.x;
  __shared__ float xt[64][65];
  {
    int nl = tid & 63, c4 = tid >> 6;
    #pragma unroll
    for (int i = 0; i < 16; ++i) {
      int c = c4 * 16 + i;
      xt[c][nl] = inp[((size_t)(b*CC + c))*NN + n0 + nl];
    }
  }
  __syncthreads();
  {
    int nl = tid >> 2, cq = tid & 3;
    unsigned int pk[8];
    #pragma unroll
    for (int i = 0; i < 8; ++i) {
      int c = cq*16 + i*2;
      pk[i] = pkbf(xt[c][nl], xt[c+1][nl]);
    }
    unsigned int* dst = (unsigned int*)(xTb + (((size_t)b*NN) + n0 + nl)*CC + cq*16);
    ((int4*)dst)[0] = make_int4((int)pk[0],(int)pk[1],(int)pk[2],(int)pk[3]);
    ((int4*)dst)[1] = make_int4((int)pk[4],(int)pk[5],(int)pk[6],(int)pk[7]);
  }
}

// ---------------------------------------------------------------------------
// Prep 2: conv weights (T,O,C,K) f32 -> (T,O,576) bf16, col = k*64 + c
// ---------------------------------------------------------------------------
__global__ __launch_bounds__(256) void wprep_kernel(
    const float* __restrict__ cw, unsigned short* __restrict__ W3)
{
  const int k = blockIdx.x;  // 0..8
  const int t = blockIdx.y;  // 0..3
  for (int u = threadIdx.x; u < OO*CC; u += 256) {
    int o = u >> 6, c = u & 63;
    float w = cw[(((size_t)(t*OO + o))*CC + c)*KK + k];
    W3[((size_t)(t*OO + o))*576 + k*64 + c] = f2bf(w);
  }
}

// ---------------------------------------------------------------------------
// Conv: n-tile 128, waves 2x2 (32o x 64n each), full C-resident accumulation.
// NO atomics: partial BN sums -> cpart[slot][128] (slot-indexed, one writer).
// ---------------------------------------------------------------------------
__global__ __launch_bounds__(256, 4) void conv_kernel(
    const unsigned short* __restrict__ xTb,  // (B,N,C) bf16
    const float* __restrict__ mc,            // (B,3,N,T)
    const int*   __restrict__ ind,           // (B,N,T)
    const unsigned short* __restrict__ W3,   // (T,O,576) bf16
    unsigned short* __restrict__ Y,          // (B,N,T,O) bf16
    float* __restrict__ cpart)               // (4096,128) partial sums
{
  const int n0  = blockIdx.x * 128;
  const int b   = blockIdx.y;
  const int t   = blockIdx.z;
  const int tid = threadIdx.x;
  const int lane = tid & 63;
  const int w    = tid >> 6;
  const int l15  = lane & 15;
  const int q    = lane >> 4;
  const int ow   = w & 1;     // o half  (32 o's)
  const int nw   = w >> 1;    // n half  (64 n's)

  __shared__ __align__(16) char U[34816];
  __shared__ float sred[2][4][64];
  short* xg   = (short*)U;                    // [136][72]
  float* wgl  = (float*)(U + 19584);          // [128][10]
  float* cxyz = (float*)(U + 19584 + 5120);   // [3][128]
  float* stage = (float*)U;                   // [128][68]

  // phase 1: center coords + gather
  for (int u = tid; u < 384; u += 256) {
    int d = u >> 7, nl = u & 127;
    cxyz[d*128 + nl] = mc[(((size_t)(b*3+d))*NN + n0 + nl)*TT + t];
  }
  for (int u = tid; u < 1088; u += 256) {
    int p = u >> 3, s = u & 7;
    int m = n0 + p - PADW;
    int4 v = make_int4(0,0,0,0);
    if (m >= 0 && m < NN) {
      int idx = ind[((size_t)b*NN + m)*TT + t];
      v = *(const int4*)(xTb + ((size_t)b*NN + idx)*CC + s*8);
    }
    *(int4*)&xg[p*72 + s*8] = v;
  }
  __syncthreads();

  // phase 2: window weights
  for (int u = tid; u < 1152; u += 256) {
    int k = u >> 7, nl = u & 127;
    int m = n0 + nl + k - PADW;
    float px = 0.f, py = 0.f, pz = 0.f;
    if (m >= 0 && m < NN) {
      px = mc[(((size_t)(b*3+0))*NN + m)*TT + t];
      py = mc[(((size_t)(b*3+1))*NN + m)*TT + t];
      pz = mc[(((size_t)(b*3+2))*NN + m)*TT + t];
    }
    float dx = px - cxyz[0*128+nl];
    float dy = py - cxyz[1*128+nl];
    float dz = pz - cxyz[2*128+nl];
    float s2 = dx*dx + dy*dy + dz*dz;
    float r = (s2 > 0.f) ? sqrtf(s2) : 0.f;
    wgl[nl*10 + k] = fmaxf(1.f - r*(1.f/SIGMA), 0.f);
  }
  __syncthreads();

  // phase 3: MFMA compute
  const unsigned short* Wbase = W3 + (size_t)t*OO*576;
  const f32x4 Z = {0.f, 0.f, 0.f, 0.f};
  f32x4 fin[2][4];
  #pragma unroll
  for (int ot = 0; ot < 2; ++ot)
    #pragma unroll
    for (int ns = 0; ns < 4; ++ns) fin[ot][ns] = Z;

  for (int k = 0; k < KK; ++k) {
    bf16x8 af[2][2];
    #pragma unroll
    for (int ot = 0; ot < 2; ++ot) {
      const unsigned short* ap =
          Wbase + (size_t)(ow*32 + ot*16 + l15)*576 + k*64 + q*8;
      af[ot][0] = *(const bf16x8*)(ap);
      af[ot][1] = *(const bf16x8*)(ap + 32);
    }
    #pragma unroll
    for (int ns = 0; ns < 4; ++ns) {
      int nl = nw*64 + ns*16 + l15;
      int p  = nl + k;
      bf16x8 b0 = *(const bf16x8*)&xg[p*72 + q*8];
      bf16x8 b1 = *(const bf16x8*)&xg[p*72 + 32 + q*8];
      float wgt = wgl[nl*10 + k];
      #pragma unroll
      for (int ot = 0; ot < 2; ++ot) {
        f32x4 d = __builtin_amdgcn_mfma_f32_16x16x32_bf16(af[ot][0], b0, Z, 0, 0, 0);
        d = __builtin_amdgcn_mfma_f32_16x16x32_bf16(af[ot][1], b1, d, 0, 0, 0);
        fin[ot][ns] += wgt * d;
      }
    }
  }
  __syncthreads();   // xg/wgl dead, reuse as stage

  // epilogue: stage[n][o] fp32, stride 68
  #pragma unroll
  for (int ot = 0; ot < 2; ++ot)
    #pragma unroll
    for (int ns = 0; ns < 4; ++ns) {
      int nl = nw*64 + ns*16 + l15;
      *(f32x4*)&stage[nl*68 + ow*32 + ot*16 + q*4] = fin[ot][ns];
    }
  __syncthreads();

  // per-(t,o) partial stats -> slot-indexed write (no atomics)
  {
    int o = tid & 63, j = tid >> 6;
    float s1 = 0.f, s2 = 0.f;
    #pragma unroll
    for (int i = 0; i < 32; ++i) {
      float v = stage[(j*32 + i)*68 + o];
      s1 += v; s2 += v*v;
    }
    sred[0][j][o] = s1;
    sred[1][j][o] = s2;
  }
  __syncthreads();
  if (tid < 64) {
    float a  = sred[0][0][tid]+sred[0][1][tid]+sred[0][2][tid]+sred[0][3][tid];
    float qq = sred[1][0][tid]+sred[1][1][tid]+sred[1][2][tid]+sred[1][3][tid];
    int slot = (t*BB + b)*256 + blockIdx.x;      // slots for t: [t*1024, t*1024+1024)
    float2 pr; pr.x = a; pr.y = qq;
    *(float2*)&cpart[(size_t)slot*128 + tid*2] = pr;
  }

  // Y store (B,N,T,O): thread -> (n = tid>>1, o-half = tid&1), 64 B each
  {
    int n = tid >> 1, h = tid & 1;
    const float* src = stage + n*68 + h*32;
    int4 st[4];
    #pragma unroll
    for (int j = 0; j < 4; ++j) {
      float4 a  = *(const float4*)(src + j*8);
      float4 b2 = *(const float4*)(src + j*8 + 4);
      st[j] = make_int4((int)pkbf(a.x,a.y), (int)pkbf(a.z,a.w),
                        (int)pkbf(b2.x,b2.y), (int)pkbf(b2.z,b2.w));
    }
    int4* dst = (int4*)(Y + (((size_t)b*NN + n0 + n)*TT + t)*OO + h*32);
    #pragma unroll
    for (int j = 0; j < 4; ++j) dst[j] = st[j];
  }
}

// ---------------------------------------------------------------------------
// Reduce conv partials -> per-(t,o) scale/shift.  Grid: 256 blocks = (t,o).
// ---------------------------------------------------------------------------
__global__ __launch_bounds__(256) void bnparam_kernel(
    const float* __restrict__ cpart,   // (4096,128)
    const float* __restrict__ gam,
    const float* __restrict__ bet,
    float* __restrict__ ss)            // (T*O,2)
{
  const int to = blockIdx.x;
  const int t = to >> 6, o = to & 63;
  const int tid = threadIdx.x;
  __shared__ float r1[256], r2[256];
  float s1 = 0.f, s2 = 0.f;
  for (int s = tid; s < 1024; s += 256) {
    const float* p = cpart + ((size_t)(t*1024 + s))*128 + o*2;
    s1 += p[0]; s2 += p[1];
  }
  r1[tid] = s1; r2[tid] = s2;
  __syncthreads();
  for (int st = 128; st > 0; st >>= 1) {
    if (tid < st) { r1[tid] += r1[tid+st]; r2[tid] += r2[tid+st]; }
    __syncthreads();
  }
  if (tid == 0) {
    const float inv = 1.f / (float)(BB * NN);
    float mean = r1[0] * inv;
    float var  = r2[0] * inv - mean * mean;
    float sc = gam[to] * rsqrtf(var + EPS_BN);
    ss[to*2 + 0] = sc;
    ss[to*2 + 1] = bet[to] - mean * sc;
  }
}

// ---------------------------------------------------------------------------
// Fusion: n-tile 128, K=256 in two staged halves, C-resident accumulation.
// NO stats here (done by fstat pass on the output).
// ---------------------------------------------------------------------------
__global__ __launch_bounds__(256, 4) void fusion_kernel(
    const unsigned short* __restrict__ Y,   // (B,N,T,O) bf16
    const int*   __restrict__ rind,         // (B,N,T)
    const float* __restrict__ ss,           // (T*O,2)
    const float* __restrict__ fw,           // (O,256) f32
    const float* __restrict__ fb,           // (O)
    float* __restrict__ out)                // (B,O,N) pre-BN
{
  const int n0  = blockIdx.x * 128;
  const int b   = blockIdx.y;
  const int tid = threadIdx.x;
  const int lane = tid & 63;
  const int w    = tid >> 6;
  const int l15  = lane & 15;
  const int q    = lane >> 4;
  const int ow   = w & 1;
  const int nw   = w >> 1;

  // union: zg short[128][136] (34816 B)  vs  stage float[64][132] (33792 B)
  __shared__ __align__(16) char U[34816];
  __shared__ int   rnl[TT][128];
  __shared__ float ssl[512];
  short* zg = (short*)U;
  float* stage = (float*)U;

  for (int u = tid; u < 512; u += 256) {
    int tt = u >> 7, nl = u & 127;
    rnl[tt][nl] = rind[((size_t)b*NN + n0 + nl)*TT + tt];
  }
  ssl[tid]       = ss[tid];
  ssl[tid + 256] = ss[tid + 256];
  __syncthreads();

  f32x4 fin[2][4];
  #pragma unroll
  for (int ot = 0; ot < 2; ++ot)
    #pragma unroll
    for (int ns = 0; ns < 4; ++ns) fin[ot][ns] = (f32x4){0.f,0.f,0.f,0.f};

  for (int h = 0; h < 2; ++h) {
    if (h) __syncthreads();
    for (int u = tid; u < 2048; u += 256) {
      int n = u >> 4, tl = (u >> 3) & 1, s = u & 7;
      int tt = h*2 + tl;
      int rn = rnl[tt][n];
      int4 raw = *(const int4*)(Y + (((size_t)b*NN + rn)*TT + tt)*OO + s*8);
      const unsigned short* rp = (const unsigned short*)&raw;
      int cb = tt*64 + s*8;
      unsigned int pk[4];
      #pragma unroll
      for (int i = 0; i < 4; ++i) {
        float v0 = bf2f(rp[2*i  ]) * ssl[(cb+2*i  )*2] + ssl[(cb+2*i  )*2+1];
        float v1 = bf2f(rp[2*i+1]) * ssl[(cb+2*i+1)*2] + ssl[(cb+2*i+1)*2+1];
        pk[i] = pkbf(v0, v1);
      }
      *(int4*)&zg[n*136 + tl*64 + s*8] =
          make_int4((int)pk[0],(int)pk[1],(int)pk[2],(int)pk[3]);
    }
    __syncthreads();

    #pragma unroll
    for (int kk = 0; kk < 4; ++kk) {
      bf16x8 af[2];
      #pragma unroll
      for (int ot = 0; ot < 2; ++ot) {
        const float* wp = fw + (size_t)(ow*32 + ot*16 + l15)*256 + h*128 + kk*32 + q*8;
        float4 wa = *(const float4*)wp;
        float4 wb = *(const float4*)(wp + 4);
        unsigned int u0 = pkbf(wa.x, wa.y), u1 = pkbf(wa.z, wa.w);
        unsigned int u2 = pkbf(wb.x, wb.y), u3 = pkbf(wb.z, wb.w);
        int4 tmp = make_int4((int)u0,(int)u1,(int)u2,(int)u3);
        __builtin_memcpy(&af[ot], &tmp, 16);
      }
      #pragma unroll
      for (int ns = 0; ns < 4; ++ns) {
        int nl = nw*64 + ns*16 + l15;
        bf16x8 bfr = *(const bf16x8*)&zg[nl*136 + kk*32 + q*8];
        #pragma unroll
        for (int ot = 0; ot < 2; ++ot)
          fin[ot][ns] = __builtin_amdgcn_mfma_f32_16x16x32_bf16(af[ot], bfr, fin[ot][ns], 0, 0, 0);
      }
    }
  }
  __syncthreads();   // zg dead, reuse as stage

  // epilogue: stage[o][n] stride 132, add bias
  #pragma unroll
  for (int ot = 0; ot < 2; ++ot) {
    #pragma unroll
    for (int r = 0; r < 4; ++r) {
      int o = ow*32 + ot*16 + q*4 + r;
      float bias = fb[o];
      #pragma unroll
      for (int ns = 0; ns < 4; ++ns) {
        int nl = nw*64 + ns*16 + l15;
        stage[o*132 + nl] = fin[ot][ns][r] + bias;
      }
    }
  }
  __syncthreads();

  {
    int o = tid >> 2, jj = tid & 3;
    const float* src = stage + o*132 + jj*32;
    float* dst = out + ((size_t)(b*OO + o))*NN + n0 + jj*32;
    #pragma unroll
    for (int i = 0; i < 8; ++i) ((float4*)dst)[i] = ((const float4*)src)[i];
  }
}

// ---------------------------------------------------------------------------
// Fusion-BN stats pass over the pre-BN output.  Grid (O, B), slot-indexed.
// ---------------------------------------------------------------------------
__global__ __launch_bounds__(256) void fstat_kernel(
    const float* __restrict__ out, float* __restrict__ fpart)  // (B*O,2)
{
  const int o = blockIdx.x, b = blockIdx.y;
  const int tid = threadIdx.x;
  __shared__ float r1[256], r2[256];
  const float* src = out + ((size_t)(b*OO + o))*NN;
  float s1 = 0.f, s2 = 0.f;
  for (int i = tid*4; i < NN; i += 1024) {
    float4 v = *(const float4*)(src + i);
    s1 += v.x + v.y + v.z + v.w;
    s2 += v.x*v.x + v.y*v.y + v.z*v.z + v.w*v.w;
  }
  r1[tid] = s1; r2[tid] = s2;
  __syncthreads();
  for (int st = 128; st > 0; st >>= 1) {
    if (tid < st) { r1[tid] += r1[tid+st]; r2[tid] += r2[tid+st]; }
    __syncthreads();
  }
  if (tid == 0) {
    fpart[(b*OO + o)*2 + 0] = r1[0];
    fpart[(b*OO + o)*2 + 1] = r2[0];
  }
}

// ---------------------------------------------------------------------------
// Fold fusion partials -> per-o scale/shift.  1 block, 64 threads.
// ---------------------------------------------------------------------------
__global__ void freduce_kernel(
    const float* __restrict__ fpart,
    const float* __restrict__ fg,
    const float* __restrict__ fbeta,
    float* __restrict__ fss)
{
  int o = threadIdx.x;   // 64
  float s1 = 0.f, s2 = 0.f;
  #pragma unroll
  for (int b = 0; b < BB; ++b) {
    s1 += fpart[(b*OO + o)*2 + 0];
    s2 += fpart[(b*OO + o)*2 + 1];
  }
  const float inv = 1.f / (float)(BB * NN);
  float mean = s1 * inv;
  float var  = s2 * inv - mean * mean;
  float sc = fg[o] * rsqrtf(var + EPS_BN);
  fss[o*2 + 0] = sc;
  fss[o*2 + 1] = fbeta[o] - mean * sc;
}

// ---------------------------------------------------------------------------
// fusion BN + relu, in place
// ---------------------------------------------------------------------------
__global__ __launch_bounds__(256) void final_kernel(
    float* __restrict__ out, const float* __restrict__ fss)
{
  const int e0 = blockIdx.x * 2048 + threadIdx.x;
  #pragma unroll
  for (int s = 0; s < 8; ++s) {
    int e  = e0 + s * 256;
    int o2 = (e >> 15) & 63;
    float sc = fss[o2*2 + 0];
    float sh = fss[o2*2 + 1];
    float v = out[e] * sc + sh;
    out[e] = fmaxf(v, 0.f);
  }
}

// ---------------------------------------------------------------------------
extern "C" void kernel_launch(void* const* d_in, const int* in_sizes, int n_in,
                              void* d_out, int out_size, void* d_ws, size_t ws_size,
                              hipStream_t stream) {
  const float* inp  = (const float*)d_in[0];
  const float* mc   = (const float*)d_in[1];
  const int*   ind  = (const int*)  d_in[2];
  const int*   rind = (const int*)  d_in[3];
  const float* cw   = (const float*)d_in[4];
  const float* bg   = (const float*)d_in[5];
  const float* bb   = (const float*)d_in[6];
  const float* fw   = (const float*)d_in[7];
  const float* fb   = (const float*)d_in[8];
  const float* fg   = (const float*)d_in[9];
  const float* fbt  = (const float*)d_in[10];

  // ws: [0,2048) convss | [2048,2560) fss | [2560,4608) fpart | [8192,+64MiB) Y
  char* ws = (char*)d_ws;
  float* convss = (float*)(ws + 0);
  float* fss    = (float*)(ws + 2048);
  float* fpart  = (float*)(ws + 2560);
  unsigned short* Y = (unsigned short*)(ws + 8192);

  // scratch in d_out (all dead before fusion writes it):
  char* ob = (char*)d_out;
  unsigned short* xTb = (unsigned short*)ob;                 // 16,777,216 B
  unsigned short* W3  = (unsigned short*)(ob + 16777216);    //    294,912 B
  float*          cpart = (float*)(ob + 17072128);           //  2,097,152 B
  float* out = (float*)d_out;

  dim3 gt(NN/64, BB);
  transpose_kernel<<<gt, 256, 0, stream>>>(inp, xTb);

  dim3 gw(KK, TT);
  wprep_kernel<<<gw, 256, 0, stream>>>(cw, W3);

  dim3 gc(NN/128, BB, TT);
  conv_kernel<<<gc, 256, 0, stream>>>(xTb, mc, ind, W3, Y, cpart);

  bnparam_kernel<<<256, 256, 0, stream>>>(cpart, bg, bb, convss);

  dim3 gf(NN/128, BB);
  fusion_kernel<<<gf, 256, 0, stream>>>(Y, rind, convss, fw, fb, out);

  dim3 gs(OO, BB);
  fstat_kernel<<<gs, 256, 0, stream>>>(out, fpart);

  freduce_kernel<<<1, 64, 0, stream>>>(fpart, fg, fbt, fss);

  final_kernel<<<(BB*OO*NN)/2048, 256, 0, stream>>>(out, fss);
}

// Round 5
// 267.611 us; speedup vs baseline: 6.4974x; 1.0611x over previous
//
#include <hip/hip_runtime.h>
#include <hip/hip_bf16.h>

#define BB 4
#define CC 64
#define OO 64
#define NN 32768
#define TT 4
#define KK 9
#define PADW 4
#define SIGMA 0.05f
#define EPS_BN 1e-5f

typedef __attribute__((ext_vector_type(8))) short bf16x8;
typedef __attribute__((ext_vector_type(4))) float f32x4;

__device__ __forceinline__ unsigned short f2bf(float f) {
  __hip_bfloat16 h = __float2bfloat16(f);
  return *reinterpret_cast<unsigned short*>(&h);
}
__device__ __forceinline__ float bf2f(unsigned short u) {
  unsigned int x = ((unsigned int)u) << 16;
  float f;
  __builtin_memcpy(&f, &x, 4);
  return f;
}
__device__ __forceinline__ unsigned int pkbf(float a, float b) {
  float2 t; t.x = a; t.y = b;
  __hip_bfloat162 h = __float22bfloat162_rn(t);
  unsigned int r;
  __builtin_memcpy(&r, &h, 4);
  return r;
}

// ---------------------------------------------------------------------------
// Prep 1: transpose input (B,C,N) f32 -> (B,N,C) bf16
// ---------------------------------------------------------------------------
__global__ __launch_bounds__(256) void transpose_kernel(
    const float* __restrict__ inp, unsigned short* __restrict__ xTb)
{
  const int n0 = blockIdx.x * 64;
  const int b  = blockIdx.y;
  const int tid = threadIdx.x;
  __shared__ float xt[64][65];
  {
    int nl = tid & 63, c4 = tid >> 6;
    #pragma unroll
    for (int i = 0; i < 16; ++i) {
      int c = c4 * 16 + i;
      xt[c][nl] = inp[((size_t)(b*CC + c))*NN + n0 + nl];
    }
  }
  __syncthreads();
  {
    int nl = tid >> 2, cq = tid & 3;
    unsigned int pk[8];
    #pragma unroll
    for (int i = 0; i < 8; ++i) {
      int c = cq*16 + i*2;
      pk[i] = pkbf(xt[c][nl], xt[c+1][nl]);
    }
    unsigned int* dst = (unsigned int*)(xTb + (((size_t)b*NN) + n0 + nl)*CC + cq*16);
    ((int4*)dst)[0] = make_int4((int)pk[0],(int)pk[1],(int)pk[2],(int)pk[3]);
    ((int4*)dst)[1] = make_int4((int)pk[4],(int)pk[5],(int)pk[6],(int)pk[7]);
  }
}

// ---------------------------------------------------------------------------
// Prep 2: conv weights (T,O,C,K) f32 -> (T,O,576) bf16, col = k*64 + c
// ---------------------------------------------------------------------------
__global__ __launch_bounds__(256) void wprep_kernel(
    const float* __restrict__ cw, unsigned short* __restrict__ W3)
{
  const int k = blockIdx.x;  // 0..8
  const int t = blockIdx.y;  // 0..3
  for (int u = threadIdx.x; u < OO*CC; u += 256) {
    int o = u >> 6, c = u & 63;
    float w = cw[(((size_t)(t*OO + o))*CC + c)*KK + k];
    W3[((size_t)(t*OO + o))*576 + k*64 + c] = f2bf(w);
  }
}

// ---------------------------------------------------------------------------
// Conv: n-tile 128, waves 2x2 (32o x 64n each). ONE barrier; register epilogue
// (direct Y stores + shfl-butterfly stats -> cpart2[(t,o)][2][4096]).
// ---------------------------------------------------------------------------
__global__ __launch_bounds__(256, 4) void conv_kernel(
    const unsigned short* __restrict__ xTb,  // (B,N,C) bf16
    const float* __restrict__ mc,            // (B,3,N,T)
    const int*   __restrict__ ind,           // (B,N,T)
    const unsigned short* __restrict__ W3,   // (T,O,576) bf16
    unsigned short* __restrict__ Y,          // (B,N,T,O) bf16
    float* __restrict__ cpart2)              // (256 to, 2, 4096 slots)
{
  const int n0  = blockIdx.x * 128;
  const int b   = blockIdx.y;
  const int t   = blockIdx.z;
  const int tid = threadIdx.x;
  const int lane = tid & 63;
  const int w    = tid >> 6;
  const int l15  = lane & 15;
  const int q    = lane >> 4;
  const int ow   = w & 1;     // o half  (32 o's)
  const int nw   = w >> 1;    // n half  (64 n's)

  __shared__ short xg[136][72];      // gathered window rows (bf16 bits), 19584 B
  __shared__ float wgl[128][10];     // window weights, 5120 B

  // --- phase A: issue gather loads into registers (latency overlapped below)
  int4 g[5];
  #pragma unroll
  for (int i = 0; i < 5; ++i) {
    int u = tid + 256*i;
    g[i] = make_int4(0,0,0,0);
    if (u < 1088) {
      int p = u >> 3, s = u & 7;
      int m = n0 + p - PADW;
      if (m >= 0 && m < NN) {
        int idx = ind[((size_t)b*NN + m)*TT + t];
        g[i] = *(const int4*)(xTb + ((size_t)b*NN + idx)*CC + s*8);
      }
    }
  }

  // --- phase B (overlaps gather latency): window weights, thread -> (nl, k-half)
  {
    int nl = tid >> 1;
    int k0 = (tid & 1) * 5;
    int k1 = k0 + 5 - (tid & 1);
    int n = n0 + nl;
    float cx = mc[(((size_t)(b*3+0))*NN + n)*TT + t];
    float cy = mc[(((size_t)(b*3+1))*NN + n)*TT + t];
    float cz = mc[(((size_t)(b*3+2))*NN + n)*TT + t];
    for (int k = k0; k < k1; ++k) {
      int m = n + k - PADW;
      float px = 0.f, py = 0.f, pz = 0.f;
      if (m >= 0 && m < NN) {
        px = mc[(((size_t)(b*3+0))*NN + m)*TT + t];
        py = mc[(((size_t)(b*3+1))*NN + m)*TT + t];
        pz = mc[(((size_t)(b*3+2))*NN + m)*TT + t];
      }
      float dx = px-cx, dy = py-cy, dz = pz-cz;
      float s2 = dx*dx + dy*dy + dz*dz;
      float r = (s2 > 0.f) ? sqrtf(s2) : 0.f;
      wgl[nl][k] = fmaxf(1.f - r*(1.f/SIGMA), 0.f);
    }
  }

  // --- commit gather to LDS
  #pragma unroll
  for (int i = 0; i < 5; ++i) {
    int u = tid + 256*i;
    if (u < 1088) {
      int p = u >> 3, s = u & 7;
      *(int4*)&xg[p][s*8] = g[i];
    }
  }
  __syncthreads();   // the only block-wide barrier

  // --- MFMA loop
  const unsigned short* Wbase = W3 + (size_t)t*OO*576;
  const f32x4 Z = {0.f, 0.f, 0.f, 0.f};
  f32x4 fin[2][4];
  #pragma unroll
  for (int ot = 0; ot < 2; ++ot)
    #pragma unroll
    for (int ns = 0; ns < 4; ++ns) fin[ot][ns] = Z;

  for (int k = 0; k < KK; ++k) {
    bf16x8 af[2][2];
    #pragma unroll
    for (int ot = 0; ot < 2; ++ot) {
      const unsigned short* ap =
          Wbase + (size_t)(ow*32 + ot*16 + l15)*576 + k*64 + q*8;
      af[ot][0] = *(const bf16x8*)(ap);
      af[ot][1] = *(const bf16x8*)(ap + 32);
    }
    #pragma unroll
    for (int ns = 0; ns < 4; ++ns) {
      int nl = nw*64 + ns*16 + l15;
      int p  = nl + k;
      bf16x8 b0 = *(const bf16x8*)&xg[p][q*8];
      bf16x8 b1 = *(const bf16x8*)&xg[p][32 + q*8];
      float wgt = wgl[nl][k];
      #pragma unroll
      for (int ot = 0; ot < 2; ++ot) {
        f32x4 d = __builtin_amdgcn_mfma_f32_16x16x32_bf16(af[ot][0], b0, Z, 0, 0, 0);
        d = __builtin_amdgcn_mfma_f32_16x16x32_bf16(af[ot][1], b1, d, 0, 0, 0);
        fin[ot][ns] += wgt * d;
      }
    }
  }

  // --- register epilogue 1: direct Y stores (B,N,T,O)
  #pragma unroll
  for (int ns = 0; ns < 4; ++ns) {
    int nl = nw*64 + ns*16 + l15;
    size_t row = (((size_t)b*NN + n0 + nl)*TT + t)*OO;
    #pragma unroll
    for (int ot = 0; ot < 2; ++ot) {
      uint2 pk2;
      pk2.x = pkbf(fin[ot][ns][0], fin[ot][ns][1]);
      pk2.y = pkbf(fin[ot][ns][2], fin[ot][ns][3]);
      *(uint2*)(Y + row + ow*32 + ot*16 + q*4) = pk2;
    }
  }

  // --- register epilogue 2: stats via shfl butterfly (width 16 = l15 group)
  float sv[16];
  #pragma unroll
  for (int ot = 0; ot < 2; ++ot)
    #pragma unroll
    for (int r = 0; r < 4; ++r) {
      float a = 0.f, qs = 0.f;
      #pragma unroll
      for (int ns = 0; ns < 4; ++ns) {
        float v = fin[ot][ns][r];
        a += v; qs += v*v;
      }
      sv[ot*4+r] = a; sv[8+ot*4+r] = qs;
    }
  #pragma unroll
  for (int msk = 1; msk < 16; msk <<= 1) {
    #pragma unroll
    for (int i = 0; i < 16; ++i) sv[i] += __shfl_xor(sv[i], msk, 16);
  }
  if (l15 == 0) {
    int slot4 = ((b*256 + (int)blockIdx.x) << 2) | w;   // [0,4096)
    #pragma unroll
    for (int ot = 0; ot < 2; ++ot)
      #pragma unroll
      for (int r = 0; r < 4; ++r) {
        int o = ow*32 + ot*16 + q*4 + r;
        cpart2[((size_t)((t*64 + o)*2 + 0))*4096 + slot4] = sv[ot*4+r];
        cpart2[((size_t)((t*64 + o)*2 + 1))*4096 + slot4] = sv[8+ot*4+r];
      }
  }
}

// ---------------------------------------------------------------------------
// Reduce conv partials -> per-(t,o) scale/shift.  Grid 256 = (t,o).
// ---------------------------------------------------------------------------
__global__ __launch_bounds__(256) void bnparam_kernel(
    const float* __restrict__ cpart2,  // (256,2,4096)
    const float* __restrict__ gam,
    const float* __restrict__ bet,
    float* __restrict__ ss)            // (T*O,2)
{
  const int to = blockIdx.x;
  const int tid = threadIdx.x;
  __shared__ float r1[256], r2[256];
  const float* p1 = cpart2 + (size_t)to*2*4096;
  const float* p2 = p1 + 4096;
  float s1 = 0.f, s2 = 0.f;
  for (int i = tid*4; i < 4096; i += 1024) {
    float4 a = *(const float4*)(p1 + i);
    float4 c = *(const float4*)(p2 + i);
    s1 += a.x + a.y + a.z + a.w;
    s2 += c.x + c.y + c.z + c.w;
  }
  r1[tid] = s1; r2[tid] = s2;
  __syncthreads();
  for (int st = 128; st > 0; st >>= 1) {
    if (tid < st) { r1[tid] += r1[tid+st]; r2[tid] += r2[tid+st]; }
    __syncthreads();
  }
  if (tid == 0) {
    const float inv = 1.f / (float)(BB * NN);
    float mean = r1[0] * inv;
    float var  = r2[0] * inv - mean * mean;
    float sc = gam[to] * rsqrtf(var + EPS_BN);
    ss[to*2 + 0] = sc;
    ss[to*2 + 1] = bet[to] - mean * sc;
  }
}

// ---------------------------------------------------------------------------
// Fusion: n-tile 128, K=256 in 4 quarter-rounds (t = round), reg epilogue.
// ---------------------------------------------------------------------------
__global__ __launch_bounds__(256, 4) void fusion_kernel(
    const unsigned short* __restrict__ Y,   // (B,N,T,O) bf16
    const int*   __restrict__ rind,         // (B,N,T)
    const float* __restrict__ ss,           // (T*O,2)
    const float* __restrict__ fw,           // (O,256) f32
    const float* __restrict__ fb,           // (O)
    float* __restrict__ out)                // (B,O,N) pre-BN
{
  const int n0  = blockIdx.x * 128;
  const int b   = blockIdx.y;
  const int tid = threadIdx.x;
  const int lane = tid & 63;
  const int w    = tid >> 6;
  const int l15  = lane & 15;
  const int q    = lane >> 4;
  const int ow   = w & 1;
  const int nw   = w >> 1;

  __shared__ short zg[128][72];     // one K-quarter (= one t) of staged rows
  __shared__ int   rnl[TT][128];
  __shared__ float ssl[512];

  for (int u = tid; u < 512; u += 256) {
    int tt = u >> 7, nl = u & 127;
    rnl[tt][nl] = rind[((size_t)b*NN + n0 + nl)*TT + tt];
  }
  ssl[tid]       = ss[tid];
  ssl[tid + 256] = ss[tid + 256];
  __syncthreads();

  f32x4 fin[2][4];
  #pragma unroll
  for (int ot = 0; ot < 2; ++ot)
    #pragma unroll
    for (int ns = 0; ns < 4; ++ns) fin[ot][ns] = (f32x4){0.f,0.f,0.f,0.f};

  for (int r = 0; r < 4; ++r) {     // K-quarter == t index
    if (r) __syncthreads();
    // stage 128 rows x 128B of Y[.,rn,r,.] with BN affine
    #pragma unroll
    for (int i = 0; i < 4; ++i) {
      int u = tid + 256*i;          // < 1024
      int n = u >> 3, s = u & 7;
      int rn = rnl[r][n];
      int4 raw = *(const int4*)(Y + (((size_t)b*NN + rn)*TT + r)*OO + s*8);
      const unsigned short* rp = (const unsigned short*)&raw;
      int cb = r*64 + s*8;
      unsigned int pk[4];
      #pragma unroll
      for (int j = 0; j < 4; ++j) {
        float v0 = bf2f(rp[2*j  ]) * ssl[(cb+2*j  )*2] + ssl[(cb+2*j  )*2+1];
        float v1 = bf2f(rp[2*j+1]) * ssl[(cb+2*j+1)*2] + ssl[(cb+2*j+1)*2+1];
        pk[j] = pkbf(v0, v1);
      }
      *(int4*)&zg[n][s*8] = make_int4((int)pk[0],(int)pk[1],(int)pk[2],(int)pk[3]);
    }
    __syncthreads();

    #pragma unroll
    for (int kk = 0; kk < 2; ++kk) {
      bf16x8 af[2];
      #pragma unroll
      for (int ot = 0; ot < 2; ++ot) {
        const float* wp = fw + (size_t)(ow*32 + ot*16 + l15)*256 + r*64 + kk*32 + q*8;
        float4 wa = *(const float4*)wp;
        float4 wb = *(const float4*)(wp + 4);
        unsigned int u0 = pkbf(wa.x, wa.y), u1 = pkbf(wa.z, wa.w);
        unsigned int u2 = pkbf(wb.x, wb.y), u3 = pkbf(wb.z, wb.w);
        int4 tmp = make_int4((int)u0,(int)u1,(int)u2,(int)u3);
        __builtin_memcpy(&af[ot], &tmp, 16);
      }
      #pragma unroll
      for (int ns = 0; ns < 4; ++ns) {
        int nl = nw*64 + ns*16 + l15;
        bf16x8 bfr = *(const bf16x8*)&zg[nl][kk*32 + q*8];
        #pragma unroll
        for (int ot = 0; ot < 2; ++ot)
          fin[ot][ns] = __builtin_amdgcn_mfma_f32_16x16x32_bf16(af[ot], bfr, fin[ot][ns], 0, 0, 0);
      }
    }
  }

  // register epilogue: direct coalesced stores (4 o-rows x 64B per inst)
  #pragma unroll
  for (int ot = 0; ot < 2; ++ot)
    #pragma unroll
    for (int rr = 0; rr < 4; ++rr) {
      int o = ow*32 + ot*16 + q*4 + rr;
      float bias = fb[o];
      float* dst = out + ((size_t)(b*OO + o))*NN + n0 + nw*64;
      #pragma unroll
      for (int ns = 0; ns < 4; ++ns)
        dst[ns*16 + l15] = fin[ot][ns][rr] + bias;
    }
}

// ---------------------------------------------------------------------------
// Fusion-BN stats pass over the pre-BN output.  Grid (O, B).
// ---------------------------------------------------------------------------
__global__ __launch_bounds__(256) void fstat_kernel(
    const float* __restrict__ out, float* __restrict__ fpart)  // (B*O,2)
{
  const int o = blockIdx.x, b = blockIdx.y;
  const int tid = threadIdx.x;
  __shared__ float r1[256], r2[256];
  const float* src = out + ((size_t)(b*OO + o))*NN;
  float s1 = 0.f, s2 = 0.f;
  for (int i = tid*4; i < NN; i += 1024) {
    float4 v = *(const float4*)(src + i);
    s1 += v.x + v.y + v.z + v.w;
    s2 += v.x*v.x + v.y*v.y + v.z*v.z + v.w*v.w;
  }
  r1[tid] = s1; r2[tid] = s2;
  __syncthreads();
  for (int st = 128; st > 0; st >>= 1) {
    if (tid < st) { r1[tid] += r1[tid+st]; r2[tid] += r2[tid+st]; }
    __syncthreads();
  }
  if (tid == 0) {
    fpart[(b*OO + o)*2 + 0] = r1[0];
    fpart[(b*OO + o)*2 + 1] = r2[0];
  }
}

// ---------------------------------------------------------------------------
// Fold fusion partials -> per-o scale/shift.  1 block, 64 threads.
// ---------------------------------------------------------------------------
__global__ void freduce_kernel(
    const float* __restrict__ fpart,
    const float* __restrict__ fg,
    const float* __restrict__ fbeta,
    float* __restrict__ fss)
{
  int o = threadIdx.x;   // 64
  float s1 = 0.f, s2 = 0.f;
  #pragma unroll
  for (int b = 0; b < BB; ++b) {
    s1 += fpart[(b*OO + o)*2 + 0];
    s2 += fpart[(b*OO + o)*2 + 1];
  }
  const float inv = 1.f / (float)(BB * NN);
  float mean = s1 * inv;
  float var  = s2 * inv - mean * mean;
  float sc = fg[o] * rsqrtf(var + EPS_BN);
  fss[o*2 + 0] = sc;
  fss[o*2 + 1] = fbeta[o] - mean * sc;
}

// ---------------------------------------------------------------------------
// fusion BN + relu, in place
// ---------------------------------------------------------------------------
__global__ __launch_bounds__(256) void final_kernel(
    float* __restrict__ out, const float* __restrict__ fss)
{
  const int e0 = blockIdx.x * 2048 + threadIdx.x;
  #pragma unroll
  for (int s = 0; s < 8; ++s) {
    int e  = e0 + s * 256;
    int o2 = (e >> 15) & 63;
    float sc = fss[o2*2 + 0];
    float sh = fss[o2*2 + 1];
    float v = out[e] * sc + sh;
    out[e] = fmaxf(v, 0.f);
  }
}

// ---------------------------------------------------------------------------
extern "C" void kernel_launch(void* const* d_in, const int* in_sizes, int n_in,
                              void* d_out, int out_size, void* d_ws, size_t ws_size,
                              hipStream_t stream) {
  const float* inp  = (const float*)d_in[0];
  const float* mc   = (const float*)d_in[1];
  const int*   ind  = (const int*)  d_in[2];
  const int*   rind = (const int*)  d_in[3];
  const float* cw   = (const float*)d_in[4];
  const float* bg   = (const float*)d_in[5];
  const float* bb   = (const float*)d_in[6];
  const float* fw   = (const float*)d_in[7];
  const float* fb   = (const float*)d_in[8];
  const float* fg   = (const float*)d_in[9];
  const float* fbt  = (const float*)d_in[10];

  // ws: [0,2048) convss | [2048,2560) fss | [2560,4608) fpart | [8192,+64MiB) Y
  char* ws = (char*)d_ws;
  float* convss = (float*)(ws + 0);
  float* fss    = (float*)(ws + 2048);
  float* fpart  = (float*)(ws + 2560);
  unsigned short* Y = (unsigned short*)(ws + 8192);

  // scratch in d_out (all dead before fusion writes it):
  char* ob = (char*)d_out;
  unsigned short* xTb = (unsigned short*)ob;                 // 16,777,216 B
  unsigned short* W3  = (unsigned short*)(ob + 16777216);    //    294,912 B
  float*          cpart2 = (float*)(ob + 17072128);          //  8,388,608 B
  float* out = (float*)d_out;

  dim3 gt(NN/64, BB);
  transpose_kernel<<<gt, 256, 0, stream>>>(inp, xTb);

  dim3 gw(KK, TT);
  wprep_kernel<<<gw, 256, 0, stream>>>(cw, W3);

  dim3 gc(NN/128, BB, TT);
  conv_kernel<<<gc, 256, 0, stream>>>(xTb, mc, ind, W3, Y, cpart2);

  bnparam_kernel<<<256, 256, 0, stream>>>(cpart2, bg, bb, convss);

  dim3 gf(NN/128, BB);
  fusion_kernel<<<gf, 256, 0, stream>>>(Y, rind, convss, fw, fb, out);

  dim3 gs(OO, BB);
  fstat_kernel<<<gs, 256, 0, stream>>>(out, fpart);

  freduce_kernel<<<1, 64, 0, stream>>>(fpart, fg, fbt, fss);

  final_kernel<<<(BB*OO*NN)/2048, 256, 0, stream>>>(out, fss);
}

// Round 6
// 238.252 us; speedup vs baseline: 7.2980x; 1.1232x over previous
//
#include <hip/hip_runtime.h>
#include <hip/hip_bf16.h>

#define BB 4
#define CC 64
#define OO 64
#define NN 32768
#define TT 4
#define KK 9
#define PADW 4
#define SIGMA 0.05f
#define EPS_BN 1e-5f

typedef __attribute__((ext_vector_type(8))) short bf16x8;
typedef __attribute__((ext_vector_type(4))) float f32x4;

__device__ __forceinline__ unsigned short f2bf(float f) {
  __hip_bfloat16 h = __float2bfloat16(f);
  return *reinterpret_cast<unsigned short*>(&h);
}
__device__ __forceinline__ float bf2f(unsigned short u) {
  unsigned int x = ((unsigned int)u) << 16;
  float f;
  __builtin_memcpy(&f, &x, 4);
  return f;
}
__device__ __forceinline__ unsigned int pkbf(float a, float b) {
  float2 t; t.x = a; t.y = b;
  __hip_bfloat162 h = __float22bfloat162_rn(t);
  unsigned int r;
  __builtin_memcpy(&r, &h, 4);
  return r;
}

// ---------------------------------------------------------------------------
// Prep 1: transpose input (B,C,N) f32 -> (B,N,C) bf16
// ---------------------------------------------------------------------------
__global__ __launch_bounds__(256) void transpose_kernel(
    const float* __restrict__ inp, unsigned short* __restrict__ xTb)
{
  const int n0 = blockIdx.x * 64;
  const int b  = blockIdx.y;
  const int tid = threadIdx.x;
  __shared__ float xt[64][65];
  {
    int nl = tid & 63, c4 = tid >> 6;
    #pragma unroll
    for (int i = 0; i < 16; ++i) {
      int c = c4 * 16 + i;
      xt[c][nl] = inp[((size_t)(b*CC + c))*NN + n0 + nl];
    }
  }
  __syncthreads();
  {
    int nl = tid >> 2, cq = tid & 3;
    unsigned int pk[8];
    #pragma unroll
    for (int i = 0; i < 8; ++i) {
      int c = cq*16 + i*2;
      pk[i] = pkbf(xt[c][nl], xt[c+1][nl]);
    }
    unsigned int* dst = (unsigned int*)(xTb + (((size_t)b*NN) + n0 + nl)*CC + cq*16);
    ((int4*)dst)[0] = make_int4((int)pk[0],(int)pk[1],(int)pk[2],(int)pk[3]);
    ((int4*)dst)[1] = make_int4((int)pk[4],(int)pk[5],(int)pk[6],(int)pk[7]);
  }
}

// ---------------------------------------------------------------------------
// Prep 2: conv weights (T,O,C,K) f32 -> fragment-order bf16
//   W4[(t*9+k)*4096 + ow*2048 + ot*1024 + frag*512 + l15*32 + q*8 + j]
//   so a wave's af load is one contiguous 1 KB chunk.
// ---------------------------------------------------------------------------
__global__ __launch_bounds__(256) void wprep_kernel(
    const float* __restrict__ cw, unsigned short* __restrict__ W4)
{
  const int k = blockIdx.x;  // 0..8
  const int t = blockIdx.y;  // 0..3
  for (int u = threadIdx.x; u < OO*CC; u += 256) {
    int o = u >> 6, c = u & 63;
    int ow = o >> 5, ot = (o >> 4) & 1, l15 = o & 15;
    int frag = c >> 5, q = (c >> 3) & 3, j = c & 7;
    float wv = cw[(((size_t)(t*OO + o))*CC + c)*KK + k];
    W4[(size_t)(t*9+k)*4096 + ow*2048 + ot*1024 + frag*512 + l15*32 + q*8 + j]
        = f2bf(wv);
  }
}

// ---------------------------------------------------------------------------
// Conv: n-tile 128, waves 2x2 (32o x 64n each).
// Coalesced mc staging via LDS; fragment-order W4; contiguous Y region (T,B,N,O).
// ---------------------------------------------------------------------------
__global__ __launch_bounds__(256, 4) void conv_kernel(
    const unsigned short* __restrict__ xTb,  // (B,N,C) bf16
    const float* __restrict__ mc,            // (B,3,N,T)
    const int*   __restrict__ ind,           // (B,N,T)
    const unsigned short* __restrict__ W4,   // fragment-order bf16
    unsigned short* __restrict__ Y,          // (T,B,N,O) bf16
    float* __restrict__ cpart2)              // (256 to, 2, 4096 slots)
{
  const int n0  = blockIdx.x * 128;
  const int b   = blockIdx.y;
  const int t   = blockIdx.z;
  const int tid = threadIdx.x;
  const int lane = tid & 63;
  const int w    = tid >> 6;
  const int l15  = lane & 15;
  const int q    = lane >> 4;
  const int ow   = w & 1;     // o half  (32 o's)
  const int nw   = w >> 1;    // n half  (64 n's)

  __shared__ short xg[136][72];      // gathered window rows (bf16 bits)
  __shared__ float wgl[128][10];     // window weights
  __shared__ float mcs[3][140];      // coords for this t, zero-padded

  // --- phase A: issue gather loads into registers
  int4 g[5];
  #pragma unroll
  for (int i = 0; i < 5; ++i) {
    int u = tid + 256*i;
    g[i] = make_int4(0,0,0,0);
    if (u < 1088) {
      int p = u >> 3, s = u & 7;
      int m = n0 + p - PADW;
      if (m >= 0 && m < NN) {
        int idx = ind[((size_t)b*NN + m)*TT + t];
        g[i] = *(const int4*)(xTb + ((size_t)b*NN + idx)*CC + s*8);
      }
    }
  }

  // --- phase B: coalesced mc staging (lane=point, 16B covers all 4 t)
  if (tid < 136) {
    int m = n0 + tid - PADW;
    #pragma unroll
    for (int d = 0; d < 3; ++d) {
      float4 v = make_float4(0.f, 0.f, 0.f, 0.f);
      if (m >= 0 && m < NN)
        v = *(const float4*)(mc + (((size_t)(b*3+d))*NN + m)*TT);
      mcs[d][tid] = (t==0) ? v.x : (t==1) ? v.y : (t==2) ? v.z : v.w;
    }
  }

  // --- commit gather to LDS
  #pragma unroll
  for (int i = 0; i < 5; ++i) {
    int u = tid + 256*i;
    if (u < 1088) {
      int p = u >> 3, s = u & 7;
      *(int4*)&xg[p][s*8] = g[i];
    }
  }
  __syncthreads();

  // --- phase C: window weights from LDS coords
  // (OOB coords are zero-padded like the ref; wgt there multiplies a zero x row)
  {
    int nl = tid >> 1;
    int k0 = (tid & 1) * 5;
    int kc = 5 - (tid & 1);
    float cx = mcs[0][nl+4], cy = mcs[1][nl+4], cz = mcs[2][nl+4];
    for (int i2 = 0; i2 < kc; ++i2) {
      int k = k0 + i2, mi = nl + k;
      float dx = mcs[0][mi]-cx, dy = mcs[1][mi]-cy, dz = mcs[2][mi]-cz;
      float s2 = dx*dx + dy*dy + dz*dz;
      float r = (s2 > 0.f) ? sqrtf(s2) : 0.f;
      wgl[nl][k] = fmaxf(1.f - r*(1.f/SIGMA), 0.f);
    }
  }
  __syncthreads();

  // --- MFMA loop (af loads are contiguous 1 KB wave-loads now)
  const unsigned short* Wt = W4 + (size_t)t*9*4096 + ow*2048 + (l15*4 + q)*8;
  const f32x4 Z = {0.f, 0.f, 0.f, 0.f};
  f32x4 fin[2][4];
  #pragma unroll
  for (int ot = 0; ot < 2; ++ot)
    #pragma unroll
    for (int ns = 0; ns < 4; ++ns) fin[ot][ns] = Z;

  for (int k = 0; k < KK; ++k) {
    const unsigned short* Wk = Wt + (size_t)k*4096;
    bf16x8 af[2][2];
    #pragma unroll
    for (int ot = 0; ot < 2; ++ot) {
      af[ot][0] = *(const bf16x8*)(Wk + ot*1024);
      af[ot][1] = *(const bf16x8*)(Wk + ot*1024 + 512);
    }
    #pragma unroll
    for (int ns = 0; ns < 4; ++ns) {
      int nl = nw*64 + ns*16 + l15;
      int p  = nl + k;
      bf16x8 b0 = *(const bf16x8*)&xg[p][q*8];
      bf16x8 b1 = *(const bf16x8*)&xg[p][32 + q*8];
      float wgt = wgl[nl][k];
      #pragma unroll
      for (int ot = 0; ot < 2; ++ot) {
        f32x4 d = __builtin_amdgcn_mfma_f32_16x16x32_bf16(af[ot][0], b0, Z, 0, 0, 0);
        d = __builtin_amdgcn_mfma_f32_16x16x32_bf16(af[ot][1], b1, d, 0, 0, 0);
        fin[ot][ns] += wgt * d;
      }
    }
  }

  // --- register epilogue 1: direct Y stores, (T,B,N,O): block-contiguous 16 KB
  #pragma unroll
  for (int ns = 0; ns < 4; ++ns) {
    int nl = nw*64 + ns*16 + l15;
    size_t row = (((size_t)t*BB + b)*NN + n0 + nl)*OO;
    #pragma unroll
    for (int ot = 0; ot < 2; ++ot) {
      uint2 pk2;
      pk2.x = pkbf(fin[ot][ns][0], fin[ot][ns][1]);
      pk2.y = pkbf(fin[ot][ns][2], fin[ot][ns][3]);
      *(uint2*)(Y + row + ow*32 + ot*16 + q*4) = pk2;
    }
  }

  // --- register epilogue 2: stats via shfl butterfly (width 16)
  float sv[16];
  #pragma unroll
  for (int ot = 0; ot < 2; ++ot)
    #pragma unroll
    for (int r = 0; r < 4; ++r) {
      float a = 0.f, qs = 0.f;
      #pragma unroll
      for (int ns = 0; ns < 4; ++ns) {
        float v = fin[ot][ns][r];
        a += v; qs += v*v;
      }
      sv[ot*4+r] = a; sv[8+ot*4+r] = qs;
    }
  #pragma unroll
  for (int msk = 1; msk < 16; msk <<= 1) {
    #pragma unroll
    for (int i = 0; i < 16; ++i) sv[i] += __shfl_xor(sv[i], msk, 16);
  }
  if (l15 == 0) {
    int slot4 = ((b*256 + (int)blockIdx.x) << 2) | w;   // [0,4096)
    #pragma unroll
    for (int ot = 0; ot < 2; ++ot)
      #pragma unroll
      for (int r = 0; r < 4; ++r) {
        int o = ow*32 + ot*16 + q*4 + r;
        cpart2[((size_t)((t*64 + o)*2 + 0))*4096 + slot4] = sv[ot*4+r];
        cpart2[((size_t)((t*64 + o)*2 + 1))*4096 + slot4] = sv[8+ot*4+r];
      }
  }
}

// ---------------------------------------------------------------------------
// Reduce conv partials -> per-(t,o) scale/shift.  Grid 256 = (t,o).
// ---------------------------------------------------------------------------
__global__ __launch_bounds__(256) void bnparam_kernel(
    const float* __restrict__ cpart2,  // (256,2,4096)
    const float* __restrict__ gam,
    const float* __restrict__ bet,
    float* __restrict__ ss)            // (T*O,2)
{
  const int to = blockIdx.x;
  const int tid = threadIdx.x;
  __shared__ float r1[256], r2[256];
  const float* p1 = cpart2 + (size_t)to*2*4096;
  const float* p2 = p1 + 4096;
  float s1 = 0.f, s2 = 0.f;
  for (int i = tid*4; i < 4096; i += 1024) {
    float4 a = *(const float4*)(p1 + i);
    float4 c = *(const float4*)(p2 + i);
    s1 += a.x + a.y + a.z + a.w;
    s2 += c.x + c.y + c.z + c.w;
  }
  r1[tid] = s1; r2[tid] = s2;
  __syncthreads();
  for (int st = 128; st > 0; st >>= 1) {
    if (tid < st) { r1[tid] += r1[tid+st]; r2[tid] += r2[tid+st]; }
    __syncthreads();
  }
  if (tid == 0) {
    const float inv = 1.f / (float)(BB * NN);
    float mean = r1[0] * inv;
    float var  = r2[0] * inv - mean * mean;
    float sc = gam[to] * rsqrtf(var + EPS_BN);
    ss[to*2 + 0] = sc;
    ss[to*2 + 1] = bet[to] - mean * sc;
  }
}

// ---------------------------------------------------------------------------
// Fusion: n-tile 128, K=256 in 4 quarter-rounds (t = round), reg epilogue.
// ---------------------------------------------------------------------------
__global__ __launch_bounds__(256, 4) void fusion_kernel(
    const unsigned short* __restrict__ Y,   // (T,B,N,O) bf16
    const int*   __restrict__ rind,         // (B,N,T)
    const float* __restrict__ ss,           // (T*O,2)
    const float* __restrict__ fw,           // (O,256) f32
    const float* __restrict__ fb,           // (O)
    float* __restrict__ out)                // (B,O,N) pre-BN
{
  const int n0  = blockIdx.x * 128;
  const int b   = blockIdx.y;
  const int tid = threadIdx.x;
  const int lane = tid & 63;
  const int w    = tid >> 6;
  const int l15  = lane & 15;
  const int q    = lane >> 4;
  const int ow   = w & 1;
  const int nw   = w >> 1;

  __shared__ short zg[128][72];     // one K-quarter (= one t) of staged rows
  __shared__ int   rnl[TT][128];
  __shared__ float ssl[512];

  for (int u = tid; u < 512; u += 256) {
    int tt = u >> 7, nl = u & 127;
    rnl[tt][nl] = rind[((size_t)b*NN + n0 + nl)*TT + tt];
  }
  ssl[tid]       = ss[tid];
  ssl[tid + 256] = ss[tid + 256];
  __syncthreads();

  f32x4 fin[2][4];
  #pragma unroll
  for (int ot = 0; ot < 2; ++ot)
    #pragma unroll
    for (int ns = 0; ns < 4; ++ns) fin[ot][ns] = (f32x4){0.f,0.f,0.f,0.f};

  for (int r = 0; r < 4; ++r) {     // K-quarter == t index
    if (r) __syncthreads();
    // stage 128 rows x 128B of Y[r,b,rn,.] with BN affine
    #pragma unroll
    for (int i = 0; i < 4; ++i) {
      int u = tid + 256*i;          // < 1024
      int n = u >> 3, s = u & 7;
      int rn = rnl[r][n];
      int4 raw = *(const int4*)(Y + (((size_t)r*BB + b)*NN + rn)*OO + s*8);
      const unsigned short* rp = (const unsigned short*)&raw;
      int cb = r*64 + s*8;
      unsigned int pk[4];
      #pragma unroll
      for (int j = 0; j < 4; ++j) {
        float v0 = bf2f(rp[2*j  ]) * ssl[(cb+2*j  )*2] + ssl[(cb+2*j  )*2+1];
        float v1 = bf2f(rp[2*j+1]) * ssl[(cb+2*j+1)*2] + ssl[(cb+2*j+1)*2+1];
        pk[j] = pkbf(v0, v1);
      }
      *(int4*)&zg[n][s*8] = make_int4((int)pk[0],(int)pk[1],(int)pk[2],(int)pk[3]);
    }
    __syncthreads();

    #pragma unroll
    for (int kk = 0; kk < 2; ++kk) {
      bf16x8 af[2];
      #pragma unroll
      for (int ot = 0; ot < 2; ++ot) {
        const float* wp = fw + (size_t)(ow*32 + ot*16 + l15)*256 + r*64 + kk*32 + q*8;
        float4 wa = *(const float4*)wp;
        float4 wb = *(const float4*)(wp + 4);
        unsigned int u0 = pkbf(wa.x, wa.y), u1 = pkbf(wa.z, wa.w);
        unsigned int u2 = pkbf(wb.x, wb.y), u3 = pkbf(wb.z, wb.w);
        int4 tmp = make_int4((int)u0,(int)u1,(int)u2,(int)u3);
        __builtin_memcpy(&af[ot], &tmp, 16);
      }
      #pragma unroll
      for (int ns = 0; ns < 4; ++ns) {
        int nl = nw*64 + ns*16 + l15;
        bf16x8 bfr = *(const bf16x8*)&zg[nl][kk*32 + q*8];
        #pragma unroll
        for (int ot = 0; ot < 2; ++ot)
          fin[ot][ns] = __builtin_amdgcn_mfma_f32_16x16x32_bf16(af[ot], bfr, fin[ot][ns], 0, 0, 0);
      }
    }
  }

  // register epilogue: direct coalesced stores
  #pragma unroll
  for (int ot = 0; ot < 2; ++ot)
    #pragma unroll
    for (int rr = 0; rr < 4; ++rr) {
      int o = ow*32 + ot*16 + q*4 + rr;
      float bias = fb[o];
      float* dst = out + ((size_t)(b*OO + o))*NN + n0 + nw*64;
      #pragma unroll
      for (int ns = 0; ns < 4; ++ns)
        dst[ns*16 + l15] = fin[ot][ns][rr] + bias;
    }
}

// ---------------------------------------------------------------------------
// Fusion-BN stats pass over the pre-BN output.  Grid (O, B).
// ---------------------------------------------------------------------------
__global__ __launch_bounds__(256) void fstat_kernel(
    const float* __restrict__ out, float* __restrict__ fpart)  // (B*O,2)
{
  const int o = blockIdx.x, b = blockIdx.y;
  const int tid = threadIdx.x;
  __shared__ float r1[256], r2[256];
  const float* src = out + ((size_t)(b*OO + o))*NN;
  float s1 = 0.f, s2 = 0.f;
  for (int i = tid*4; i < NN; i += 1024) {
    float4 v = *(const float4*)(src + i);
    s1 += v.x + v.y + v.z + v.w;
    s2 += v.x*v.x + v.y*v.y + v.z*v.z + v.w*v.w;
  }
  r1[tid] = s1; r2[tid] = s2;
  __syncthreads();
  for (int st = 128; st > 0; st >>= 1) {
    if (tid < st) { r1[tid] += r1[tid+st]; r2[tid] += r2[tid+st]; }
    __syncthreads();
  }
  if (tid == 0) {
    fpart[(b*OO + o)*2 + 0] = r1[0];
    fpart[(b*OO + o)*2 + 1] = r2[0];
  }
}

// ---------------------------------------------------------------------------
// Fold fusion partials -> per-o scale/shift.  1 block, 64 threads.
// ---------------------------------------------------------------------------
__global__ void freduce_kernel(
    const float* __restrict__ fpart,
    const float* __restrict__ fg,
    const float* __restrict__ fbeta,
    float* __restrict__ fss)
{
  int o = threadIdx.x;   // 64
  float s1 = 0.f, s2 = 0.f;
  #pragma unroll
  for (int b = 0; b < BB; ++b) {
    s1 += fpart[(b*OO + o)*2 + 0];
    s2 += fpart[(b*OO + o)*2 + 1];
  }
  const float inv = 1.f / (float)(BB * NN);
  float mean = s1 * inv;
  float var  = s2 * inv - mean * mean;
  float sc = fg[o] * rsqrtf(var + EPS_BN);
  fss[o*2 + 0] = sc;
  fss[o*2 + 1] = fbeta[o] - mean * sc;
}

// ---------------------------------------------------------------------------
// fusion BN + relu, in place
// ---------------------------------------------------------------------------
__global__ __launch_bounds__(256) void final_kernel(
    float* __restrict__ out, const float* __restrict__ fss)
{
  const int e0 = blockIdx.x * 2048 + threadIdx.x;
  #pragma unroll
  for (int s = 0; s < 8; ++s) {
    int e  = e0 + s * 256;
    int o2 = (e >> 15) & 63;
    float sc = fss[o2*2 + 0];
    float sh = fss[o2*2 + 1];
    float v = out[e] * sc + sh;
    out[e] = fmaxf(v, 0.f);
  }
}

// ---------------------------------------------------------------------------
extern "C" void kernel_launch(void* const* d_in, const int* in_sizes, int n_in,
                              void* d_out, int out_size, void* d_ws, size_t ws_size,
                              hipStream_t stream) {
  const float* inp  = (const float*)d_in[0];
  const float* mc   = (const float*)d_in[1];
  const int*   ind  = (const int*)  d_in[2];
  const int*   rind = (const int*)  d_in[3];
  const float* cw   = (const float*)d_in[4];
  const float* bg   = (const float*)d_in[5];
  const float* bb   = (const float*)d_in[6];
  const float* fw   = (const float*)d_in[7];
  const float* fb   = (const float*)d_in[8];
  const float* fg   = (const float*)d_in[9];
  const float* fbt  = (const float*)d_in[10];

  // ws: [0,2048) convss | [2048,2560) fss | [2560,4608) fpart | [8192,+64MiB) Y
  char* ws = (char*)d_ws;
  float* convss = (float*)(ws + 0);
  float* fss    = (float*)(ws + 2048);
  float* fpart  = (float*)(ws + 2560);
  unsigned short* Y = (unsigned short*)(ws + 8192);   // (T,B,N,O)

  // scratch in d_out (all dead before fusion writes it):
  char* ob = (char*)d_out;
  unsigned short* xTb = (unsigned short*)ob;                 // 16,777,216 B
  unsigned short* W4  = (unsigned short*)(ob + 16777216);    //    294,912 B
  float*          cpart2 = (float*)(ob + 17072128);          //  8,388,608 B
  float* out = (float*)d_out;

  dim3 gt(NN/64, BB);
  transpose_kernel<<<gt, 256, 0, stream>>>(inp, xTb);

  dim3 gw(KK, TT);
  wprep_kernel<<<gw, 256, 0, stream>>>(cw, W4);

  dim3 gc(NN/128, BB, TT);
  conv_kernel<<<gc, 256, 0, stream>>>(xTb, mc, ind, W4, Y, cpart2);

  bnparam_kernel<<<256, 256, 0, stream>>>(cpart2, bg, bb, convss);

  dim3 gf(NN/128, BB);
  fusion_kernel<<<gf, 256, 0, stream>>>(Y, rind, convss, fw, fb, out);

  dim3 gs(OO, BB);
  fstat_kernel<<<gs, 256, 0, stream>>>(out, fpart);

  freduce_kernel<<<1, 64, 0, stream>>>(fpart, fg, fbt, fss);

  final_kernel<<<(BB*OO*NN)/2048, 256, 0, stream>>>(out, fss);
}